// Round 17
// baseline (129.636 us; speedup 1.0000x reference)
//
#include <hip/hip_runtime.h>
#include <hip/hip_bf16.h>

typedef __attribute__((ext_vector_type(8))) short bf16x8;
typedef __attribute__((ext_vector_type(4))) float f32x4;
typedef __attribute__((ext_vector_type(16))) float f32x16;

#define MFMA16(a, b, c) __builtin_amdgcn_mfma_f32_16x16x32_bf16(a, b, c, 0, 0, 0)
#define MFMA32(a, b, c) __builtin_amdgcn_mfma_f32_32x32x16_bf16(a, b, c, 0, 0, 0)

__device__ inline ushort f2b(float f) {
  union { float f; unsigned u; } v; v.f = f;
  unsigned u = v.u;
  u += 0x7fffu + ((u >> 16) & 1u);   // round-to-nearest-even
  return (ushort)(u >> 16);
}

__device__ inline unsigned cvtpk(float lo, float hi) {
  unsigned r;
  asm("v_cvt_pk_bf16_f32 %0, %1, %2" : "=v"(r) : "v"(lo), "v"(hi));
  return r;
}

// v_permlane32_swap_b32: lanes<32 keep a.lo/get b.lo; lanes>=32 get a.hi/keep b.hi
__device__ inline void plswap(unsigned& a, unsigned& b) {
  asm("v_permlane32_swap_b32 %0, %1" : "+v"(a), "+v"(b));
}

// ---- fused cast: x -> xb, {WQ,WK,WV} -> wcat, WO -> wob ----
__global__ void prep_cast(const float* __restrict__ x,
                          const float* __restrict__ wq, const float* __restrict__ wk,
                          const float* __restrict__ wv, const float* __restrict__ wo,
                          ushort* __restrict__ xb, ushort* __restrict__ wcat,
                          ushort* __restrict__ wob) {
  const int gid = blockIdx.x * 256 + threadIdx.x;
  if (blockIdx.x < 4096) {
    const int i = gid * 4;                     // 4M floats of x
    float4 v = *reinterpret_cast<const float4*>(x + i);
    ushort4 o;
    o.x = f2b(v.x); o.y = f2b(v.y); o.z = f2b(v.z); o.w = f2b(v.w);
    *reinterpret_cast<ushort4*>(xb + i) = o;
  } else {
    const int i = (gid - 4096 * 256) * 4;      // 4M floats of weights
    const int which = i >> 20, off = i & 1048575;
    const float* src = (which == 0) ? wq : (which == 1) ? wk : (which == 2) ? wv : wo;
    float4 v = *reinterpret_cast<const float4*>(src + off);
    ushort4 o;
    o.x = f2b(v.x); o.y = f2b(v.y); o.z = f2b(v.z); o.w = f2b(v.w);
    if (which < 3) *reinterpret_cast<ushort4*>(wcat + i) = o;
    else           *reinterpret_cast<ushort4*>(wob + off) = o;
  }
}

// relF4[h][i] = { b(i), b(i-1), b(i-2), b(i-3) },  b(d) = relT[(d+2047)*16+h]*log2e
__global__ void prep_f4(const float* __restrict__ relT, float4* __restrict__ relF4) {
  const int t = blockIdx.x * 256 + threadIdx.x;   // 16*2048
  const int h = t >> 11, i = t & 2047;
  const float C = 1.4426950408889634f;
  float4 v;
  v.x = relT[(size_t)(i + 2047) * 16 + h] * C;
  v.y = (i >= 1) ? relT[(size_t)(i + 2046) * 16 + h] * C : 0.f;
  v.z = (i >= 2) ? relT[(size_t)(i + 2045) * 16 + h] * C : 0.f;
  v.w = (i >= 3) ? relT[(size_t)(i + 2044) * 16 + h] * C : 0.f;
  relF4[(size_t)h * 2048 + i] = v;
}

// ---------------- GEMM: C[M,N] = A[M,K] @ B[N,K]^T (+bias), BK=64, T2 swizzle ----
template <int MODE>
__global__ __launch_bounds__(256, 3)
void gemm_bt(const ushort* __restrict__ A, const ushort* __restrict__ B,
             const float* __restrict__ b0, const float* __restrict__ b1,
             const float* __restrict__ b2,
             float* __restrict__ outF, ushort* __restrict__ Qg,
             ushort* __restrict__ Kf, ushort* __restrict__ Vf, int N) {
  __shared__ __align__(16) ushort As[128][64];
  __shared__ __align__(16) ushort Bs[128][64];
  const int tid = threadIdx.x;
  const int m0 = blockIdx.y * 128, n0 = blockIdx.x * 128;
  const int wid = tid >> 6, lane = tid & 63, g = lane >> 4, li = lane & 15;
  const int wr = (wid >> 1) * 64, wc = (wid & 1) * 64;
  const int srow0 = (lane >> 3);
  const int scol = (((lane & 7) ^ (lane >> 3)) * 8);   // pre-swizzled source col
  f32x4 acc[4][4] = {};
  for (int k0 = 0; k0 < 1024; k0 += 64) {
#pragma unroll
    for (int it = 0; it < 4; ++it) {
      const int rb = (wid * 4 + it) * 8;
      __builtin_amdgcn_global_load_lds(
          (const __attribute__((address_space(1))) void*)(A + (size_t)(m0 + rb + srow0) * 1024 + k0 + scol),
          (__attribute__((address_space(3))) void*)(&As[0][0] + (wid * 4 + it) * 512), 16, 0, 0);
      __builtin_amdgcn_global_load_lds(
          (const __attribute__((address_space(1))) void*)(B + (size_t)(n0 + rb + srow0) * 1024 + k0 + scol),
          (__attribute__((address_space(3))) void*)(&Bs[0][0] + (wid * 4 + it) * 512), 16, 0, 0);
    }
    __syncthreads();
#pragma unroll
    for (int kk = 0; kk < 64; kk += 32) {
      bf16x8 af[4], bfm[4];
#pragma unroll
      for (int i = 0; i < 4; ++i) {
        const int cs = (kk + g * 8) ^ ((li & 7) << 3);  // swizzled read col
        af[i]  = *reinterpret_cast<const bf16x8*>(&As[wr + i * 16 + li][cs]);
        bfm[i] = *reinterpret_cast<const bf16x8*>(&Bs[wc + i * 16 + li][cs]);
      }
#pragma unroll
      for (int mi = 0; mi < 4; ++mi)
#pragma unroll
        for (int ni = 0; ni < 4; ++ni)
          acc[mi][ni] = MFMA16(af[mi], bfm[ni], acc[mi][ni]);
    }
    __syncthreads();
  }
#pragma unroll
  for (int mi = 0; mi < 4; ++mi) {
#pragma unroll
    for (int ni = 0; ni < 4; ++ni) {
      const int col = n0 + wc + ni * 16 + li;
      if (MODE == 0) {
#pragma unroll
        for (int r = 0; r < 4; ++r) {
          const int row = m0 + wr + mi * 16 + 4 * g + r;
          outF[(size_t)row * N + col] = acc[mi][ni][r] + b0[col];
        }
      } else {
        const int which = col >> 10, c = col & 1023;
        const int hh = c >> 6, dk = c & 63;
        const float* bias = (which == 0) ? b0 : ((which == 1) ? b1 : b2);
        const float bcol = bias[c];
        const int row0 = m0 + wr + mi * 16 + 4 * g;
        const int bb = row0 >> 11, t0 = row0 & 2047;  // t0 multiple of 4
        const int bhi = bb * 16 + hh;
        if (which == 0) {
          ushort* dst = Qg + ((size_t)bhi * 2048 + t0) * 64 + dk;
#pragma unroll
          for (int r = 0; r < 4; ++r)
            dst[(size_t)r * 64] = f2b(acc[mi][ni][r] + bcol);
        } else if (which == 1) {
          const size_t cb = ((size_t)((bhi * 32 + (t0 >> 6)) * 8 + ((t0 >> 5) & 1) * 4 + (dk >> 4))) * 512
                            + ((dk >> 3) & 1) * 256 + (dk & 7);
          ushort* dst = Kf + cb + (t0 & 31) * 8;
#pragma unroll
          for (int r = 0; r < 4; ++r)
            dst[r * 8] = f2b(acc[mi][ni][r] + bcol);
        } else {
          const size_t cb = ((size_t)((bhi * 32 + (t0 >> 6)) * 8 + (dk >> 5) * 4 + ((t0 >> 4) & 3))) * 512
                            + (dk & 31) * 8 + ((t0 >> 3) & 1) * 256 + (t0 & 7);
          ushort4 o;
          o.x = f2b(acc[mi][ni][0] + bcol);
          o.y = f2b(acc[mi][ni][1] + bcol);
          o.z = f2b(acc[mi][ni][2] + bcol);
          o.w = f2b(acc[mi][ni][3] + bcol);
          *reinterpret_cast<ushort4*>(Vf + cb) = o;
        }
      }
    }
  }
}

// ---------------- flash attention: paired q-tiles share K/V loads ----------------
__device__ __forceinline__ void soft_pv(
    f32x16& S0, f32x16& S1, const int dqb, const bool masked,
    const float4* __restrict__ relv4, float* lacc, f32x16* O, const bf16x8* Vr) {
  const float C1 = 0.18033688f;               // 0.125 * log2(e)
  if (!masked) {
#pragma unroll
    for (int rg = 0; rg < 4; ++rg) {
      const int i0 = dqb - 8 * rg, i1 = i0 - 32;
      const float4 bq0 = relv4[i0 ^ ((i0 >> 3) & 3)];
      const float4 bq1 = relv4[i1 ^ ((i1 >> 3) & 3)];
      const float b0e[4] = {bq0.x, bq0.y, bq0.z, bq0.w};
      const float b1e[4] = {bq1.x, bq1.y, bq1.z, bq1.w};
#pragma unroll
      for (int j = 0; j < 4; ++j) {
        const int r = 4 * rg + j;
        const float p0 = __builtin_amdgcn_exp2f(fmaf(S0[r], C1, b0e[j]));
        const float p1 = __builtin_amdgcn_exp2f(fmaf(S1[r], C1, b1e[j]));
        S0[r] = p0; S1[r] = p1;
        lacc[j] += p0 + p1;
      }
    }
  } else {
#pragma unroll
    for (int rg = 0; rg < 4; ++rg) {
      const int d0b = dqb - 8 * rg, d1b = d0b - 32;
      const int i0 = d0b & 2047, i1 = d1b & 2047;
      const float4 bq0 = relv4[i0 ^ ((i0 >> 3) & 3)];
      const float4 bq1 = relv4[i1 ^ ((i1 >> 3) & 3)];
      const float b0e[4] = {bq0.x, bq0.y, bq0.z, bq0.w};
      const float b1e[4] = {bq1.x, bq1.y, bq1.z, bq1.w};
#pragma unroll
      for (int j = 0; j < 4; ++j) {
        const int r = 4 * rg + j;
        float p0 = __builtin_amdgcn_exp2f(fmaf(S0[r], C1, b0e[j]));
        float p1 = __builtin_amdgcn_exp2f(fmaf(S1[r], C1, b1e[j]));
        p0 = (d0b - j >= 0) ? p0 : 0.f;
        p1 = (d1b - j >= 0) ? p1 : 0.f;
        S0[r] = p0; S1[r] = p1;
        lacc[j] += p0 + p1;
      }
    }
  }
  unsigned U0[4][2], U1[4][2];
#pragma unroll
  for (int rg = 0; rg < 4; ++rg) {
    U0[rg][0] = cvtpk(S0[4 * rg + 0], S0[4 * rg + 1]);
    U0[rg][1] = cvtpk(S0[4 * rg + 2], S0[4 * rg + 3]);
    U1[rg][0] = cvtpk(S1[4 * rg + 0], S1[4 * rg + 1]);
    U1[rg][1] = cvtpk(S1[4 * rg + 2], S1[4 * rg + 3]);
  }
#pragma unroll
  for (int c = 0; c < 4; ++c) {
    const int c0 = c & 1;
    unsigned x0 = (c < 2) ? U0[2 * c0][0] : U1[2 * c0][0];
    unsigned y0 = (c < 2) ? U0[2 * c0 + 1][0] : U1[2 * c0 + 1][0];
    unsigned x1 = (c < 2) ? U0[2 * c0][1] : U1[2 * c0][1];
    unsigned y1 = (c < 2) ? U0[2 * c0 + 1][1] : U1[2 * c0 + 1][1];
    plswap(x0, y0);
    plswap(x1, y1);
    union { unsigned u[4]; bf16x8 v; } P;
    P.u[0] = x0; P.u[1] = x1; P.u[2] = y0; P.u[3] = y1;
#pragma unroll
    for (int db = 0; db < 2; ++db)
      O[db] = MFMA32(Vr[db * 4 + c], P.v, O[db]);
  }
}

__device__ __forceinline__ void merge_write(
    const int wid, const int lane, const int hi, const int q,
    const int h, const int bb, f32x16* O, float* lacc,
    float Obuf[3][64][33], float lbuf[3][64], ushort* __restrict__ Oa) {
  __syncthreads();
  if (wid) {
    float* ob = &Obuf[wid - 1][lane][0];
#pragma unroll
    for (int db = 0; db < 2; ++db)
#pragma unroll
      for (int r = 0; r < 16; ++r)
        ob[db * 16 + r] = O[db][r];
    lbuf[wid - 1][lane] = lacc[0] + lacc[1] + lacc[2] + lacc[3];
  }
  __syncthreads();
  if (wid == 0) {
    float lh = lacc[0] + lacc[1] + lacc[2] + lacc[3];
#pragma unroll
    for (int w = 0; w < 3; ++w) {
      lh += lbuf[w][lane];
      const float* ob = &Obuf[w][lane][0];
#pragma unroll
      for (int db = 0; db < 2; ++db)
#pragma unroll
        for (int r = 0; r < 16; ++r)
          O[db][r] += ob[db * 16 + r];
    }
    unsigned xa = __float_as_uint(lh), xb2 = xa;
    plswap(xa, xb2);                      // xa = [lo|lo], xb2 = [hi|hi]
    const float linv = 1.f / (__uint_as_float(xa) + __uint_as_float(xb2));
    ushort* orow = Oa + ((size_t)(bb * 2048 + q)) * 1024 + h * 64;
#pragma unroll
    for (int db = 0; db < 2; ++db)
#pragma unroll
      for (int rg = 0; rg < 4; ++rg) {
        ushort4 o;
        o.x = f2b(O[db][4 * rg + 0] * linv);
        o.y = f2b(O[db][4 * rg + 1] * linv);
        o.z = f2b(O[db][4 * rg + 2] * linv);
        o.w = f2b(O[db][4 * rg + 3] * linv);
        *reinterpret_cast<ushort4*>(orow + db * 32 + 8 * rg + 4 * hi) = o;
      }
  }
}

// grid: 1024 blocks = (bh, qp). One combined k-loop; per-iteration order
// QK_B -> soft_pv(B) -> QK_A -> soft_pv(A) so SA/SB never coexist (reg pressure).
// launch_bounds min-waves=1: no implied VGPR cap (LDS is the occupancy limit).
__global__ __launch_bounds__(256, 1)
void attn_k(const ushort* __restrict__ Qg, const ushort* __restrict__ Kf,
            const ushort* __restrict__ Vf, const float4* __restrict__ relF4,
            ushort* __restrict__ Oa) {
  __shared__ __align__(16) float4 relv4[2048];
  __shared__ float Obuf[3][64][33];
  __shared__ float lbuf[3][64];
  const int f = blockIdx.x;
  const int bh = (f & 7) * 4 + (f >> 8);      // same bh -> same XCD
  const int qp = (f >> 3) & 31;
  const int h = bh & 15, bb = bh >> 4;
  {
    const float4* src = relF4 + (size_t)h * 2048;
    for (int i = threadIdx.x; i < 2048; i += 256)
      relv4[i ^ ((i >> 3) & 3)] = src[i];
  }
  __syncthreads();
  const int wid = threadIdx.x >> 6, lane = threadIdx.x & 63;
  const int li = lane & 31, hi = lane >> 5;
  const ushort* Qb  = Qg + (size_t)bh * (2048 * 64);
  const ushort* Kfb = Kf + (size_t)bh * (32 * 4096);
  const ushort* Vfb = Vf + (size_t)bh * (32 * 4096);
  const int qtA = qp, qtB = 63 - qp;
  const int qA = qtA * 32 + li, qB = qtB * 32 + li;
  bf16x8 qfA[4], qfB[4];
#pragma unroll
  for (int c = 0; c < 4; ++c) {
    qfA[c] = *reinterpret_cast<const bf16x8*>(Qb + (size_t)qA * 64 + c * 16 + hi * 8);
    qfB[c] = *reinterpret_cast<const bf16x8*>(Qb + (size_t)qB * 64 + c * 16 + hi * 8);
  }
  f32x16 OA[2] = {}, OB[2] = {};
  float laccA[4] = {0.f, 0.f, 0.f, 0.f};
  float laccB[4] = {0.f, 0.f, 0.f, 0.f};
  const int nktA = (qtA >> 1) + 1;
  const int ntA = (wid < nktA) ? ((nktA - 1 - wid) >> 2) + 1 : 0;
  const int mask_kbA = (nktA - 1) * 64;
  const int nktB = (qtB >> 1) + 1;              // >= 17 > wid always
  const int ntB = ((nktB - 1 - wid) >> 2) + 1;
  const int mask_kbB = (nktB - 1) * 64;
  for (int i = 0; i < ntB; ++i) {
    const int kb = wid * 64 + i * 256;
    const ushort* Kt = Kfb + (size_t)(kb >> 6) * 4096 + lane * 8;
    const ushort* Vt = Vfb + (size_t)(kb >> 6) * 4096 + lane * 8;
    bf16x8 Kr[8], Vr[8];
#pragma unroll
    for (int j = 0; j < 8; ++j)
      Kr[j] = *reinterpret_cast<const bf16x8*>(Kt + j * 512);
#pragma unroll
    for (int j = 0; j < 8; ++j)
      Vr[j] = *reinterpret_cast<const bf16x8*>(Vt + j * 512);
    __builtin_amdgcn_sched_barrier(0);
    {
      f32x16 SB0 = {}, SB1 = {};
#pragma unroll
      for (int c = 0; c < 4; ++c) SB0 = MFMA32(Kr[c], qfB[c], SB0);
#pragma unroll
      for (int c = 0; c < 4; ++c) SB1 = MFMA32(Kr[4 + c], qfB[c], SB1);
      soft_pv(SB0, SB1, qB - kb - 4 * hi, kb == mask_kbB, relv4, laccB, OB, Vr);
    }
    if (i < ntA) {
      f32x16 SA0 = {}, SA1 = {};
#pragma unroll
      for (int c = 0; c < 4; ++c) SA0 = MFMA32(Kr[c], qfA[c], SA0);
#pragma unroll
      for (int c = 0; c < 4; ++c) SA1 = MFMA32(Kr[4 + c], qfA[c], SA1);
      soft_pv(SA0, SA1, qA - kb - 4 * hi, kb == mask_kbA, relv4, laccA, OA, Vr);
    }
  }
  merge_write(wid, lane, hi, qA, h, bb, OA, laccA, Obuf, lbuf, Oa);
  merge_write(wid, lane, hi, qB, h, bb, OB, laccB, Obuf, lbuf, Oa);
}

extern "C" void kernel_launch(void* const* d_in, const int* in_sizes, int n_in,
                              void* d_out, int out_size, void* d_ws, size_t ws_size,
                              hipStream_t stream) {
  const float* x    = (const float*)d_in[0];
  const float* WQ   = (const float*)d_in[1];
  const float* bQ   = (const float*)d_in[2];
  const float* WK   = (const float*)d_in[3];
  const float* bK   = (const float*)d_in[4];
  const float* WV   = (const float*)d_in[5];
  const float* bV   = (const float*)d_in[6];
  const float* WO   = (const float*)d_in[7];
  const float* bO   = (const float*)d_in[8];
  const float* relT = (const float*)d_in[9];
  float* out = (float*)d_out;

  if (ws_size < (size_t)48 * 1024 * 1024) return;

  char* ws = (char*)d_ws;
  const size_t MB = 1024 * 1024;
  ushort* xb    = (ushort*)(ws);             // [4096][1024] bf16; dead after gemm1
  float4* relF4 = (float4*)(ws);             // [16][2048] f32x4 (512KB); overlays xb
  ushort* Wcat  = (ushort*)(ws + 8 * MB);    // [3072][1024] bf16
  ushort* WOb   = (ushort*)(ws + 14 * MB);   // [1024][1024] bf16
  ushort* Qg    = (ushort*)(ws + 16 * MB);   // [2,16,2048,64] bf16
  ushort* Kf    = (ushort*)(ws + 24 * MB);   // K fragment-order (8MB)
  ushort* Vf    = (ushort*)(ws + 32 * MB);   // V fragment-order (8MB)
  ushort* Oa    = (ushort*)(ws + 40 * MB);   // attn out bf16

  prep_cast<<<8192, 256, 0, stream>>>(x, WQ, WK, WV, WO, xb, Wcat, WOb);

  gemm_bt<1><<<dim3(24, 32), 256, 0, stream>>>(xb, Wcat, bQ, bK, bV,
                                               nullptr, Qg, Kf, Vf, 3072);
  prep_f4<<<128, 256, 0, stream>>>(relT, relF4);   // after gemm1: overlays dead xb
  attn_k<<<1024, 256, 0, stream>>>(Qg, Kf, Vf, relF4, Oa);
  gemm_bt<0><<<dim3(8, 32), 256, 0, stream>>>(Oa, WOb, bO, nullptr, nullptr,
                                              out, nullptr, nullptr, nullptr, 1024);
}

// Round 18
// 109.784 us; speedup vs baseline: 1.1808x; 1.1808x over previous
//
#include <hip/hip_runtime.h>
#include <hip/hip_bf16.h>

typedef __attribute__((ext_vector_type(8))) short bf16x8;
typedef __attribute__((ext_vector_type(4))) float f32x4;
typedef __attribute__((ext_vector_type(16))) float f32x16;

#define MFMA16(a, b, c) __builtin_amdgcn_mfma_f32_16x16x32_bf16(a, b, c, 0, 0, 0)
#define MFMA32(a, b, c) __builtin_amdgcn_mfma_f32_32x32x16_bf16(a, b, c, 0, 0, 0)

__device__ inline ushort f2b(float f) {
  union { float f; unsigned u; } v; v.f = f;
  unsigned u = v.u;
  u += 0x7fffu + ((u >> 16) & 1u);   // round-to-nearest-even
  return (ushort)(u >> 16);
}

__device__ inline unsigned cvtpk(float lo, float hi) {
  unsigned r;
  asm("v_cvt_pk_bf16_f32 %0, %1, %2" : "=v"(r) : "v"(lo), "v"(hi));
  return r;
}

// v_permlane32_swap_b32: lanes<32 keep a.lo/get b.lo; lanes>=32 get a.hi/keep b.hi
__device__ inline void plswap(unsigned& a, unsigned& b) {
  asm("v_permlane32_swap_b32 %0, %1" : "+v"(a), "+v"(b));
}

// ---- fused cast: x -> xb, {WQ,WK,WV} -> wcat, WO -> wob ----
__global__ void prep_cast(const float* __restrict__ x,
                          const float* __restrict__ wq, const float* __restrict__ wk,
                          const float* __restrict__ wv, const float* __restrict__ wo,
                          ushort* __restrict__ xb, ushort* __restrict__ wcat,
                          ushort* __restrict__ wob) {
  const int gid = blockIdx.x * 256 + threadIdx.x;
  if (blockIdx.x < 4096) {
    const int i = gid * 4;                     // 4M floats of x
    float4 v = *reinterpret_cast<const float4*>(x + i);
    ushort4 o;
    o.x = f2b(v.x); o.y = f2b(v.y); o.z = f2b(v.z); o.w = f2b(v.w);
    *reinterpret_cast<ushort4*>(xb + i) = o;
  } else {
    const int i = (gid - 4096 * 256) * 4;      // 4M floats of weights
    const int which = i >> 20, off = i & 1048575;
    const float* src = (which == 0) ? wq : (which == 1) ? wk : (which == 2) ? wv : wo;
    float4 v = *reinterpret_cast<const float4*>(src + off);
    ushort4 o;
    o.x = f2b(v.x); o.y = f2b(v.y); o.z = f2b(v.z); o.w = f2b(v.w);
    if (which < 3) *reinterpret_cast<ushort4*>(wcat + i) = o;
    else           *reinterpret_cast<ushort4*>(wob + off) = o;
  }
}

// relF4[h][i] = { b(i), b(i-1), b(i-2), b(i-3) },  b(d) = relT[(d+2047)*16+h]*log2e
__global__ void prep_f4(const float* __restrict__ relT, float4* __restrict__ relF4) {
  const int t = blockIdx.x * 256 + threadIdx.x;   // 16*2048
  const int h = t >> 11, i = t & 2047;
  const float C = 1.4426950408889634f;
  float4 v;
  v.x = relT[(size_t)(i + 2047) * 16 + h] * C;
  v.y = (i >= 1) ? relT[(size_t)(i + 2046) * 16 + h] * C : 0.f;
  v.z = (i >= 2) ? relT[(size_t)(i + 2045) * 16 + h] * C : 0.f;
  v.w = (i >= 3) ? relT[(size_t)(i + 2044) * 16 + h] * C : 0.f;
  relF4[(size_t)h * 2048 + i] = v;
}

// ---------------- GEMM: C[M,N] = A[M,K] @ B[N,K]^T (+bias), BK=64, T2 swizzle ----
template <int MODE>
__global__ __launch_bounds__(256, 3)
void gemm_bt(const ushort* __restrict__ A, const ushort* __restrict__ B,
             const float* __restrict__ b0, const float* __restrict__ b1,
             const float* __restrict__ b2,
             float* __restrict__ outF, ushort* __restrict__ Qg,
             ushort* __restrict__ Kf, ushort* __restrict__ Vf, int N) {
  __shared__ __align__(16) ushort As[128][64];
  __shared__ __align__(16) ushort Bs[128][64];
  const int tid = threadIdx.x;
  const int m0 = blockIdx.y * 128, n0 = blockIdx.x * 128;
  const int wid = tid >> 6, lane = tid & 63, g = lane >> 4, li = lane & 15;
  const int wr = (wid >> 1) * 64, wc = (wid & 1) * 64;
  const int srow0 = (lane >> 3);
  const int scol = (((lane & 7) ^ (lane >> 3)) * 8);   // pre-swizzled source col
  f32x4 acc[4][4] = {};
  for (int k0 = 0; k0 < 1024; k0 += 64) {
#pragma unroll
    for (int it = 0; it < 4; ++it) {
      const int rb = (wid * 4 + it) * 8;
      __builtin_amdgcn_global_load_lds(
          (const __attribute__((address_space(1))) void*)(A + (size_t)(m0 + rb + srow0) * 1024 + k0 + scol),
          (__attribute__((address_space(3))) void*)(&As[0][0] + (wid * 4 + it) * 512), 16, 0, 0);
      __builtin_amdgcn_global_load_lds(
          (const __attribute__((address_space(1))) void*)(B + (size_t)(n0 + rb + srow0) * 1024 + k0 + scol),
          (__attribute__((address_space(3))) void*)(&Bs[0][0] + (wid * 4 + it) * 512), 16, 0, 0);
    }
    __syncthreads();
#pragma unroll
    for (int kk = 0; kk < 64; kk += 32) {
      bf16x8 af[4], bfm[4];
#pragma unroll
      for (int i = 0; i < 4; ++i) {
        const int cs = (kk + g * 8) ^ ((li & 7) << 3);  // swizzled read col
        af[i]  = *reinterpret_cast<const bf16x8*>(&As[wr + i * 16 + li][cs]);
        bfm[i] = *reinterpret_cast<const bf16x8*>(&Bs[wc + i * 16 + li][cs]);
      }
#pragma unroll
      for (int mi = 0; mi < 4; ++mi)
#pragma unroll
        for (int ni = 0; ni < 4; ++ni)
          acc[mi][ni] = MFMA16(af[mi], bfm[ni], acc[mi][ni]);
    }
    __syncthreads();
  }
#pragma unroll
  for (int mi = 0; mi < 4; ++mi) {
#pragma unroll
    for (int ni = 0; ni < 4; ++ni) {
      const int col = n0 + wc + ni * 16 + li;
      if (MODE == 0) {
#pragma unroll
        for (int r = 0; r < 4; ++r) {
          const int row = m0 + wr + mi * 16 + 4 * g + r;
          outF[(size_t)row * N + col] = acc[mi][ni][r] + b0[col];
        }
      } else {
        const int which = col >> 10, c = col & 1023;
        const int hh = c >> 6, dk = c & 63;
        const float* bias = (which == 0) ? b0 : ((which == 1) ? b1 : b2);
        const float bcol = bias[c];
        const int row0 = m0 + wr + mi * 16 + 4 * g;
        const int bb = row0 >> 11, t0 = row0 & 2047;  // t0 multiple of 4
        const int bhi = bb * 16 + hh;
        if (which == 0) {
          ushort* dst = Qg + ((size_t)bhi * 2048 + t0) * 64 + dk;
#pragma unroll
          for (int r = 0; r < 4; ++r)
            dst[(size_t)r * 64] = f2b(acc[mi][ni][r] + bcol);
        } else if (which == 1) {
          const size_t cb = ((size_t)((bhi * 32 + (t0 >> 6)) * 8 + ((t0 >> 5) & 1) * 4 + (dk >> 4))) * 512
                            + ((dk >> 3) & 1) * 256 + (dk & 7);
          ushort* dst = Kf + cb + (t0 & 31) * 8;
#pragma unroll
          for (int r = 0; r < 4; ++r)
            dst[r * 8] = f2b(acc[mi][ni][r] + bcol);
        } else {
          const size_t cb = ((size_t)((bhi * 32 + (t0 >> 6)) * 8 + (dk >> 5) * 4 + ((t0 >> 4) & 3))) * 512
                            + (dk & 31) * 8 + ((t0 >> 3) & 1) * 256 + (t0 & 7);
          ushort4 o;
          o.x = f2b(acc[mi][ni][0] + bcol);
          o.y = f2b(acc[mi][ni][1] + bcol);
          o.z = f2b(acc[mi][ni][2] + bcol);
          o.w = f2b(acc[mi][ni][3] + bcol);
          *reinterpret_cast<ushort4*>(Vf + cb) = o;
        }
      }
    }
  }
}

// ---------------- flash attention: fixed-max, split-k x4, F4 vectorized bias ----
// (R14 kernel verbatim — best measured config: 41.8 us, VGPR 92, no spill.)
__device__ __forceinline__ void attn_phase(
    const int qt, const int wid, const int lane, const int li, const int hi,
    const int h, const int bb,
    const ushort* __restrict__ Qb, const ushort* __restrict__ Kfb,
    const ushort* __restrict__ Vfb, const float4* relv4,
    float Obuf[3][64][33], float lbuf[3][64], ushort* __restrict__ Oa) {
  const int q = qt * 32 + li;
  bf16x8 qf[4];
#pragma unroll
  for (int c = 0; c < 4; ++c)
    qf[c] = *reinterpret_cast<const bf16x8*>(Qb + (size_t)q * 64 + c * 16 + hi * 8);
  f32x16 O[2] = {};
  float lacc[4] = {0.f, 0.f, 0.f, 0.f};
  const int nkt = (qt >> 1) + 1;
  const int nt = (wid < nkt) ? ((nkt - 1 - wid) >> 2) + 1 : 0;
  const int mask_kb = (nkt - 1) * 64;
  const float C1 = 0.18033688f;               // 0.125 * log2(e)
  for (int i = 0; i < nt; ++i) {
    const int kb = wid * 64 + i * 256;
    const ushort* Kt = Kfb + (size_t)(kb >> 6) * 4096 + lane * 8;
    const ushort* Vt = Vfb + (size_t)(kb >> 6) * 4096 + lane * 8;
    bf16x8 Kr[8], Vr[8];
#pragma unroll
    for (int j = 0; j < 8; ++j)
      Kr[j] = *reinterpret_cast<const bf16x8*>(Kt + j * 512);
#pragma unroll
    for (int j = 0; j < 8; ++j)
      Vr[j] = *reinterpret_cast<const bf16x8*>(Vt + j * 512);
    __builtin_amdgcn_sched_barrier(0);
    f32x16 S0 = {}, S1 = {};
#pragma unroll
    for (int c = 0; c < 4; ++c) S0 = MFMA32(Kr[c], qf[c], S0);
#pragma unroll
    for (int c = 0; c < 4; ++c) S1 = MFMA32(Kr[4 + c], qf[c], S1);
    const int dqb = q - kb - 4 * hi;
    if (kb != mask_kb) {
#pragma unroll
      for (int rg = 0; rg < 4; ++rg) {
        const int i0 = dqb - 8 * rg, i1 = i0 - 32;
        const float4 bq0 = relv4[i0 ^ ((i0 >> 3) & 3)];
        const float4 bq1 = relv4[i1 ^ ((i1 >> 3) & 3)];
        const float b0e[4] = {bq0.x, bq0.y, bq0.z, bq0.w};
        const float b1e[4] = {bq1.x, bq1.y, bq1.z, bq1.w};
#pragma unroll
        for (int j = 0; j < 4; ++j) {
          const int r = 4 * rg + j;
          const float p0 = __builtin_amdgcn_exp2f(fmaf(S0[r], C1, b0e[j]));
          const float p1 = __builtin_amdgcn_exp2f(fmaf(S1[r], C1, b1e[j]));
          S0[r] = p0; S1[r] = p1;
          lacc[j] += p0 + p1;
        }
      }
    } else {
#pragma unroll
      for (int rg = 0; rg < 4; ++rg) {
        const int d0b = dqb - 8 * rg, d1b = d0b - 32;
        const int i0 = d0b & 2047, i1 = d1b & 2047;
        const float4 bq0 = relv4[i0 ^ ((i0 >> 3) & 3)];
        const float4 bq1 = relv4[i1 ^ ((i1 >> 3) & 3)];
        const float b0e[4] = {bq0.x, bq0.y, bq0.z, bq0.w};
        const float b1e[4] = {bq1.x, bq1.y, bq1.z, bq1.w};
#pragma unroll
        for (int j = 0; j < 4; ++j) {
          const int r = 4 * rg + j;
          float p0 = __builtin_amdgcn_exp2f(fmaf(S0[r], C1, b0e[j]));
          float p1 = __builtin_amdgcn_exp2f(fmaf(S1[r], C1, b1e[j]));
          p0 = (d0b - j >= 0) ? p0 : 0.f;
          p1 = (d1b - j >= 0) ? p1 : 0.f;
          S0[r] = p0; S1[r] = p1;
          lacc[j] += p0 + p1;
        }
      }
    }
    unsigned U0[4][2], U1[4][2];
#pragma unroll
    for (int rg = 0; rg < 4; ++rg) {
      U0[rg][0] = cvtpk(S0[4 * rg + 0], S0[4 * rg + 1]);
      U0[rg][1] = cvtpk(S0[4 * rg + 2], S0[4 * rg + 3]);
      U1[rg][0] = cvtpk(S1[4 * rg + 0], S1[4 * rg + 1]);
      U1[rg][1] = cvtpk(S1[4 * rg + 2], S1[4 * rg + 3]);
    }
#pragma unroll
    for (int c = 0; c < 4; ++c) {
      const int c0 = c & 1;
      unsigned x0 = (c < 2) ? U0[2 * c0][0] : U1[2 * c0][0];
      unsigned y0 = (c < 2) ? U0[2 * c0 + 1][0] : U1[2 * c0 + 1][0];
      unsigned x1 = (c < 2) ? U0[2 * c0][1] : U1[2 * c0][1];
      unsigned y1 = (c < 2) ? U0[2 * c0 + 1][1] : U1[2 * c0 + 1][1];
      plswap(x0, y0);
      plswap(x1, y1);
      union { unsigned u[4]; bf16x8 v; } P;
      P.u[0] = x0; P.u[1] = x1; P.u[2] = y0; P.u[3] = y1;
#pragma unroll
      for (int db = 0; db < 2; ++db)
        O[db] = MFMA32(Vr[db * 4 + c], P.v, O[db]);
    }
  }
  // -------- merge (pure sums: no max tracking) --------
  __syncthreads();   // also guards Obuf reuse across phases
  if (wid) {
    float* ob = &Obuf[wid - 1][lane][0];
#pragma unroll
    for (int db = 0; db < 2; ++db)
#pragma unroll
      for (int r = 0; r < 16; ++r)
        ob[db * 16 + r] = O[db][r];
    lbuf[wid - 1][lane] = lacc[0] + lacc[1] + lacc[2] + lacc[3];
  }
  __syncthreads();
  if (wid == 0) {
    float lh = lacc[0] + lacc[1] + lacc[2] + lacc[3];
#pragma unroll
    for (int w = 0; w < 3; ++w) {
      lh += lbuf[w][lane];
      const float* ob = &Obuf[w][lane][0];
#pragma unroll
      for (int db = 0; db < 2; ++db)
#pragma unroll
        for (int r = 0; r < 16; ++r)
          O[db][r] += ob[db * 16 + r];
    }
    unsigned xa = __float_as_uint(lh), xb2 = xa;
    plswap(xa, xb2);                      // xa = [lo|lo], xb2 = [hi|hi]
    const float linv = 1.f / (__uint_as_float(xa) + __uint_as_float(xb2));
    ushort* orow = Oa + ((size_t)(bb * 2048 + q)) * 1024 + h * 64;
#pragma unroll
    for (int db = 0; db < 2; ++db)
#pragma unroll
      for (int rg = 0; rg < 4; ++rg) {
        ushort4 o;
        o.x = f2b(O[db][4 * rg + 0] * linv);
        o.y = f2b(O[db][4 * rg + 1] * linv);
        o.z = f2b(O[db][4 * rg + 2] * linv);
        o.w = f2b(O[db][4 * rg + 3] * linv);
        *reinterpret_cast<ushort4*>(orow + db * 32 + 8 * rg + 4 * hi) = o;
      }
  }
}

// grid: 1024 blocks = (bh, qp); block does q-tiles qp and 63-qp -> constant work.
__global__ __launch_bounds__(256, 2)
void attn_k(const ushort* __restrict__ Qg, const ushort* __restrict__ Kf,
            const ushort* __restrict__ Vf, const float4* __restrict__ relF4,
            ushort* __restrict__ Oa) {
  __shared__ __align__(16) float4 relv4[2048];
  __shared__ float Obuf[3][64][33];
  __shared__ float lbuf[3][64];
  const int f = blockIdx.x;
  const int bh = (f & 7) * 4 + (f >> 8);      // same bh -> same XCD
  const int qp = (f >> 3) & 31;
  const int h = bh & 15, bb = bh >> 4;
  {
    const float4* src = relF4 + (size_t)h * 2048;
    for (int i = threadIdx.x; i < 2048; i += 256)
      relv4[i ^ ((i >> 3) & 3)] = src[i];
  }
  __syncthreads();
  const int wid = threadIdx.x >> 6, lane = threadIdx.x & 63;
  const int li = lane & 31, hi = lane >> 5;
  const ushort* Qb  = Qg + (size_t)bh * (2048 * 64);
  const ushort* Kfb = Kf + (size_t)bh * (32 * 4096);
  const ushort* Vfb = Vf + (size_t)bh * (32 * 4096);
  attn_phase(qp,      wid, lane, li, hi, h, bb, Qb, Kfb, Vfb, relv4, Obuf, lbuf, Oa);
  attn_phase(63 - qp, wid, lane, li, hi, h, bb, Qb, Kfb, Vfb, relv4, Obuf, lbuf, Oa);
}

extern "C" void kernel_launch(void* const* d_in, const int* in_sizes, int n_in,
                              void* d_out, int out_size, void* d_ws, size_t ws_size,
                              hipStream_t stream) {
  const float* x    = (const float*)d_in[0];
  const float* WQ   = (const float*)d_in[1];
  const float* bQ   = (const float*)d_in[2];
  const float* WK   = (const float*)d_in[3];
  const float* bK   = (const float*)d_in[4];
  const float* WV   = (const float*)d_in[5];
  const float* bV   = (const float*)d_in[6];
  const float* WO   = (const float*)d_in[7];
  const float* bO   = (const float*)d_in[8];
  const float* relT = (const float*)d_in[9];
  float* out = (float*)d_out;

  if (ws_size < (size_t)48 * 1024 * 1024) return;

  char* ws = (char*)d_ws;
  const size_t MB = 1024 * 1024;
  ushort* xb    = (ushort*)(ws);             // [4096][1024] bf16; dead after gemm1
  float4* relF4 = (float4*)(ws);             // [16][2048] f32x4 (512KB); overlays xb
  ushort* Wcat  = (ushort*)(ws + 8 * MB);    // [3072][1024] bf16
  ushort* WOb   = (ushort*)(ws + 14 * MB);   // [1024][1024] bf16
  ushort* Qg    = (ushort*)(ws + 16 * MB);   // [2,16,2048,64] bf16
  ushort* Kf    = (ushort*)(ws + 24 * MB);   // K fragment-order (8MB)
  ushort* Vf    = (ushort*)(ws + 32 * MB);   // V fragment-order (8MB)
  ushort* Oa    = (ushort*)(ws + 40 * MB);   // attn out bf16

  prep_cast<<<8192, 256, 0, stream>>>(x, WQ, WK, WV, WO, xb, Wcat, WOb);

  gemm_bt<1><<<dim3(24, 32), 256, 0, stream>>>(xb, Wcat, bQ, bK, bV,
                                               nullptr, Qg, Kf, Vf, 3072);
  prep_f4<<<128, 256, 0, stream>>>(relT, relF4);   // after gemm1: overlays dead xb
  attn_k<<<1024, 256, 0, stream>>>(Qg, Kf, Vf, relF4, Oa);
  gemm_bt<0><<<dim3(8, 32), 256, 0, stream>>>(Oa, WOb, bO, nullptr, nullptr,
                                              out, nullptr, nullptr, nullptr, 1024);
}

// Round 19
// 106.402 us; speedup vs baseline: 1.2184x; 1.0318x over previous
//
#include <hip/hip_runtime.h>
#include <hip/hip_bf16.h>

typedef __attribute__((ext_vector_type(8))) short bf16x8;
typedef __attribute__((ext_vector_type(4))) float f32x4;
typedef __attribute__((ext_vector_type(16))) float f32x16;

#define MFMA16(a, b, c) __builtin_amdgcn_mfma_f32_16x16x32_bf16(a, b, c, 0, 0, 0)
#define MFMA32(a, b, c) __builtin_amdgcn_mfma_f32_32x32x16_bf16(a, b, c, 0, 0, 0)

__device__ inline ushort f2b(float f) {
  union { float f; unsigned u; } v; v.f = f;
  unsigned u = v.u;
  u += 0x7fffu + ((u >> 16) & 1u);   // round-to-nearest-even
  return (ushort)(u >> 16);
}

__device__ inline unsigned cvtpk(float lo, float hi) {
  unsigned r;
  asm("v_cvt_pk_bf16_f32 %0, %1, %2" : "=v"(r) : "v"(lo), "v"(hi));
  return r;
}

// v_permlane32_swap_b32: lanes<32 keep a.lo/get b.lo; lanes>=32 get a.hi/keep b.hi
__device__ inline void plswap(unsigned& a, unsigned& b) {
  asm("v_permlane32_swap_b32 %0, %1" : "+v"(a), "+v"(b));
}

// ---- fused cast: x -> xb, {WQ,WK,WV} -> wcat, WO -> wob ----
__global__ void prep_cast(const float* __restrict__ x,
                          const float* __restrict__ wq, const float* __restrict__ wk,
                          const float* __restrict__ wv, const float* __restrict__ wo,
                          ushort* __restrict__ xb, ushort* __restrict__ wcat,
                          ushort* __restrict__ wob) {
  const int gid = blockIdx.x * 256 + threadIdx.x;
  if (blockIdx.x < 4096) {
    const int i = gid * 4;                     // 4M floats of x
    float4 v = *reinterpret_cast<const float4*>(x + i);
    ushort4 o;
    o.x = f2b(v.x); o.y = f2b(v.y); o.z = f2b(v.z); o.w = f2b(v.w);
    *reinterpret_cast<ushort4*>(xb + i) = o;
  } else {
    const int i = (gid - 4096 * 256) * 4;      // 4M floats of weights
    const int which = i >> 20, off = i & 1048575;
    const float* src = (which == 0) ? wq : (which == 1) ? wk : (which == 2) ? wv : wo;
    float4 v = *reinterpret_cast<const float4*>(src + off);
    ushort4 o;
    o.x = f2b(v.x); o.y = f2b(v.y); o.z = f2b(v.z); o.w = f2b(v.w);
    if (which < 3) *reinterpret_cast<ushort4*>(wcat + i) = o;
    else           *reinterpret_cast<ushort4*>(wob + off) = o;
  }
}

// relF4[h][i] = { b(i), b(i-1), b(i-2), b(i-3) },  b(d) = relT[(d+2047)*16+h]*log2e
__global__ void prep_f4(const float* __restrict__ relT, float4* __restrict__ relF4) {
  const int t = blockIdx.x * 256 + threadIdx.x;   // 16*2048
  const int h = t >> 11, i = t & 2047;
  const float C = 1.4426950408889634f;
  float4 v;
  v.x = relT[(size_t)(i + 2047) * 16 + h] * C;
  v.y = (i >= 1) ? relT[(size_t)(i + 2046) * 16 + h] * C : 0.f;
  v.z = (i >= 2) ? relT[(size_t)(i + 2045) * 16 + h] * C : 0.f;
  v.w = (i >= 3) ? relT[(size_t)(i + 2044) * 16 + h] * C : 0.f;
  relF4[(size_t)h * 2048 + i] = v;
}

// ---------------- GEMM1: QKV projection, 128x128 tile, BK=64, T2 swizzle ----
__global__ __launch_bounds__(256, 3)
void gemm_bt(const ushort* __restrict__ A, const ushort* __restrict__ B,
             const float* __restrict__ b0, const float* __restrict__ b1,
             const float* __restrict__ b2,
             ushort* __restrict__ Qg, ushort* __restrict__ Kf,
             ushort* __restrict__ Vf) {
  __shared__ __align__(16) ushort As[128][64];
  __shared__ __align__(16) ushort Bs[128][64];
  const int tid = threadIdx.x;
  const int m0 = blockIdx.y * 128, n0 = blockIdx.x * 128;
  const int wid = tid >> 6, lane = tid & 63, g = lane >> 4, li = lane & 15;
  const int wr = (wid >> 1) * 64, wc = (wid & 1) * 64;
  const int srow0 = (lane >> 3);
  const int scol = (((lane & 7) ^ (lane >> 3)) * 8);   // pre-swizzled source col
  f32x4 acc[4][4] = {};
  for (int k0 = 0; k0 < 1024; k0 += 64) {
#pragma unroll
    for (int it = 0; it < 4; ++it) {
      const int rb = (wid * 4 + it) * 8;
      __builtin_amdgcn_global_load_lds(
          (const __attribute__((address_space(1))) void*)(A + (size_t)(m0 + rb + srow0) * 1024 + k0 + scol),
          (__attribute__((address_space(3))) void*)(&As[0][0] + (wid * 4 + it) * 512), 16, 0, 0);
      __builtin_amdgcn_global_load_lds(
          (const __attribute__((address_space(1))) void*)(B + (size_t)(n0 + rb + srow0) * 1024 + k0 + scol),
          (__attribute__((address_space(3))) void*)(&Bs[0][0] + (wid * 4 + it) * 512), 16, 0, 0);
    }
    __syncthreads();
#pragma unroll
    for (int kk = 0; kk < 64; kk += 32) {
      bf16x8 af[4], bfm[4];
#pragma unroll
      for (int i = 0; i < 4; ++i) {
        const int cs = (kk + g * 8) ^ ((li & 7) << 3);  // swizzled read col
        af[i]  = *reinterpret_cast<const bf16x8*>(&As[wr + i * 16 + li][cs]);
        bfm[i] = *reinterpret_cast<const bf16x8*>(&Bs[wc + i * 16 + li][cs]);
      }
#pragma unroll
      for (int mi = 0; mi < 4; ++mi)
#pragma unroll
        for (int ni = 0; ni < 4; ++ni)
          acc[mi][ni] = MFMA16(af[mi], bfm[ni], acc[mi][ni]);
    }
    __syncthreads();
  }
#pragma unroll
  for (int mi = 0; mi < 4; ++mi) {
#pragma unroll
    for (int ni = 0; ni < 4; ++ni) {
      const int col = n0 + wc + ni * 16 + li;
      const int which = col >> 10, c = col & 1023;
      const int hh = c >> 6, dk = c & 63;
      const float* bias = (which == 0) ? b0 : ((which == 1) ? b1 : b2);
      const float bcol = bias[c];
      const int row0 = m0 + wr + mi * 16 + 4 * g;
      const int bb = row0 >> 11, t0 = row0 & 2047;  // t0 multiple of 4
      const int bhi = bb * 16 + hh;
      if (which == 0) {
        ushort* dst = Qg + ((size_t)bhi * 2048 + t0) * 64 + dk;
#pragma unroll
        for (int r = 0; r < 4; ++r)
          dst[(size_t)r * 64] = f2b(acc[mi][ni][r] + bcol);
      } else if (which == 1) {
        const size_t cb = ((size_t)((bhi * 32 + (t0 >> 6)) * 8 + ((t0 >> 5) & 1) * 4 + (dk >> 4))) * 512
                          + ((dk >> 3) & 1) * 256 + (dk & 7);
        ushort* dst = Kf + cb + (t0 & 31) * 8;
#pragma unroll
        for (int r = 0; r < 4; ++r)
          dst[r * 8] = f2b(acc[mi][ni][r] + bcol);
      } else {
        const size_t cb = ((size_t)((bhi * 32 + (t0 >> 6)) * 8 + (dk >> 5) * 4 + ((t0 >> 4) & 3))) * 512
                          + (dk & 31) * 8 + ((t0 >> 3) & 1) * 256 + (t0 & 7);
        ushort4 o;
        o.x = f2b(acc[mi][ni][0] + bcol);
        o.y = f2b(acc[mi][ni][1] + bcol);
        o.z = f2b(acc[mi][ni][2] + bcol);
        o.w = f2b(acc[mi][ni][3] + bcol);
        *reinterpret_cast<ushort4*>(Vf + cb) = o;
      }
    }
  }
}

// ---------------- GEMM2: output projection, 64x128 tile (512 blocks = 2/CU) ----
// Same staging/swizzle algebra as gemm_bt, scaled: As 8KB (2 chunks/wave),
// Bs 16KB (4 chunks/wave); 4 waves of 32x64; acc[2][4].
__global__ __launch_bounds__(256, 3)
void gemm_o(const ushort* __restrict__ A, const ushort* __restrict__ B,
            const float* __restrict__ b0, float* __restrict__ outF) {
  __shared__ __align__(16) ushort As[64][64];
  __shared__ __align__(16) ushort Bs[128][64];
  const int tid = threadIdx.x;
  const int m0 = blockIdx.y * 64, n0 = blockIdx.x * 128;
  const int wid = tid >> 6, lane = tid & 63, g = lane >> 4, li = lane & 15;
  const int wr = (wid >> 1) * 32, wc = (wid & 1) * 64;
  const int srow0 = (lane >> 3);
  const int scol = (((lane & 7) ^ (lane >> 3)) * 8);   // pre-swizzled source col
  f32x4 acc[2][4] = {};
  for (int k0 = 0; k0 < 1024; k0 += 64) {
#pragma unroll
    for (int it = 0; it < 2; ++it) {
      const int rb = (wid * 2 + it) * 8;
      __builtin_amdgcn_global_load_lds(
          (const __attribute__((address_space(1))) void*)(A + (size_t)(m0 + rb + srow0) * 1024 + k0 + scol),
          (__attribute__((address_space(3))) void*)(&As[0][0] + (wid * 2 + it) * 512), 16, 0, 0);
    }
#pragma unroll
    for (int it = 0; it < 4; ++it) {
      const int rb = (wid * 4 + it) * 8;
      __builtin_amdgcn_global_load_lds(
          (const __attribute__((address_space(1))) void*)(B + (size_t)(n0 + rb + srow0) * 1024 + k0 + scol),
          (__attribute__((address_space(3))) void*)(&Bs[0][0] + (wid * 4 + it) * 512), 16, 0, 0);
    }
    __syncthreads();
#pragma unroll
    for (int kk = 0; kk < 64; kk += 32) {
      bf16x8 af[2], bfm[4];
      const int cs = (kk + g * 8) ^ ((li & 7) << 3);  // swizzled read col
#pragma unroll
      for (int i = 0; i < 2; ++i)
        af[i] = *reinterpret_cast<const bf16x8*>(&As[wr + i * 16 + li][cs]);
#pragma unroll
      for (int i = 0; i < 4; ++i)
        bfm[i] = *reinterpret_cast<const bf16x8*>(&Bs[wc + i * 16 + li][cs]);
#pragma unroll
      for (int mi = 0; mi < 2; ++mi)
#pragma unroll
        for (int ni = 0; ni < 4; ++ni)
          acc[mi][ni] = MFMA16(af[mi], bfm[ni], acc[mi][ni]);
    }
    __syncthreads();
  }
#pragma unroll
  for (int mi = 0; mi < 2; ++mi) {
#pragma unroll
    for (int ni = 0; ni < 4; ++ni) {
      const int col = n0 + wc + ni * 16 + li;
      const float bcol = b0[col];
#pragma unroll
      for (int r = 0; r < 4; ++r) {
        const int row = m0 + wr + mi * 16 + 4 * g + r;
        outF[(size_t)row * 1024 + col] = acc[mi][ni][r] + bcol;
      }
    }
  }
}

// ---------------- flash attention: fixed-max, split-k x4, F4 vectorized bias ----
// (R14/R18 kernel verbatim — best measured config: 41.8 us, VGPR 92, no spill.)
__device__ __forceinline__ void attn_phase(
    const int qt, const int wid, const int lane, const int li, const int hi,
    const int h, const int bb,
    const ushort* __restrict__ Qb, const ushort* __restrict__ Kfb,
    const ushort* __restrict__ Vfb, const float4* relv4,
    float Obuf[3][64][33], float lbuf[3][64], ushort* __restrict__ Oa) {
  const int q = qt * 32 + li;
  bf16x8 qf[4];
#pragma unroll
  for (int c = 0; c < 4; ++c)
    qf[c] = *reinterpret_cast<const bf16x8*>(Qb + (size_t)q * 64 + c * 16 + hi * 8);
  f32x16 O[2] = {};
  float lacc[4] = {0.f, 0.f, 0.f, 0.f};
  const int nkt = (qt >> 1) + 1;
  const int nt = (wid < nkt) ? ((nkt - 1 - wid) >> 2) + 1 : 0;
  const int mask_kb = (nkt - 1) * 64;
  const float C1 = 0.18033688f;               // 0.125 * log2(e)
  for (int i = 0; i < nt; ++i) {
    const int kb = wid * 64 + i * 256;
    const ushort* Kt = Kfb + (size_t)(kb >> 6) * 4096 + lane * 8;
    const ushort* Vt = Vfb + (size_t)(kb >> 6) * 4096 + lane * 8;
    bf16x8 Kr[8], Vr[8];
#pragma unroll
    for (int j = 0; j < 8; ++j)
      Kr[j] = *reinterpret_cast<const bf16x8*>(Kt + j * 512);
#pragma unroll
    for (int j = 0; j < 8; ++j)
      Vr[j] = *reinterpret_cast<const bf16x8*>(Vt + j * 512);
    __builtin_amdgcn_sched_barrier(0);
    f32x16 S0 = {}, S1 = {};
#pragma unroll
    for (int c = 0; c < 4; ++c) S0 = MFMA32(Kr[c], qf[c], S0);
#pragma unroll
    for (int c = 0; c < 4; ++c) S1 = MFMA32(Kr[4 + c], qf[c], S1);
    const int dqb = q - kb - 4 * hi;
    if (kb != mask_kb) {
#pragma unroll
      for (int rg = 0; rg < 4; ++rg) {
        const int i0 = dqb - 8 * rg, i1 = i0 - 32;
        const float4 bq0 = relv4[i0 ^ ((i0 >> 3) & 3)];
        const float4 bq1 = relv4[i1 ^ ((i1 >> 3) & 3)];
        const float b0e[4] = {bq0.x, bq0.y, bq0.z, bq0.w};
        const float b1e[4] = {bq1.x, bq1.y, bq1.z, bq1.w};
#pragma unroll
        for (int j = 0; j < 4; ++j) {
          const int r = 4 * rg + j;
          const float p0 = __builtin_amdgcn_exp2f(fmaf(S0[r], C1, b0e[j]));
          const float p1 = __builtin_amdgcn_exp2f(fmaf(S1[r], C1, b1e[j]));
          S0[r] = p0; S1[r] = p1;
          lacc[j] += p0 + p1;
        }
      }
    } else {
#pragma unroll
      for (int rg = 0; rg < 4; ++rg) {
        const int d0b = dqb - 8 * rg, d1b = d0b - 32;
        const int i0 = d0b & 2047, i1 = d1b & 2047;
        const float4 bq0 = relv4[i0 ^ ((i0 >> 3) & 3)];
        const float4 bq1 = relv4[i1 ^ ((i1 >> 3) & 3)];
        const float b0e[4] = {bq0.x, bq0.y, bq0.z, bq0.w};
        const float b1e[4] = {bq1.x, bq1.y, bq1.z, bq1.w};
#pragma unroll
        for (int j = 0; j < 4; ++j) {
          const int r = 4 * rg + j;
          float p0 = __builtin_amdgcn_exp2f(fmaf(S0[r], C1, b0e[j]));
          float p1 = __builtin_amdgcn_exp2f(fmaf(S1[r], C1, b1e[j]));
          p0 = (d0b - j >= 0) ? p0 : 0.f;
          p1 = (d1b - j >= 0) ? p1 : 0.f;
          S0[r] = p0; S1[r] = p1;
          lacc[j] += p0 + p1;
        }
      }
    }
    unsigned U0[4][2], U1[4][2];
#pragma unroll
    for (int rg = 0; rg < 4; ++rg) {
      U0[rg][0] = cvtpk(S0[4 * rg + 0], S0[4 * rg + 1]);
      U0[rg][1] = cvtpk(S0[4 * rg + 2], S0[4 * rg + 3]);
      U1[rg][0] = cvtpk(S1[4 * rg + 0], S1[4 * rg + 1]);
      U1[rg][1] = cvtpk(S1[4 * rg + 2], S1[4 * rg + 3]);
    }
#pragma unroll
    for (int c = 0; c < 4; ++c) {
      const int c0 = c & 1;
      unsigned x0 = (c < 2) ? U0[2 * c0][0] : U1[2 * c0][0];
      unsigned y0 = (c < 2) ? U0[2 * c0 + 1][0] : U1[2 * c0 + 1][0];
      unsigned x1 = (c < 2) ? U0[2 * c0][1] : U1[2 * c0][1];
      unsigned y1 = (c < 2) ? U0[2 * c0 + 1][1] : U1[2 * c0 + 1][1];
      plswap(x0, y0);
      plswap(x1, y1);
      union { unsigned u[4]; bf16x8 v; } P;
      P.u[0] = x0; P.u[1] = x1; P.u[2] = y0; P.u[3] = y1;
#pragma unroll
      for (int db = 0; db < 2; ++db)
        O[db] = MFMA32(Vr[db * 4 + c], P.v, O[db]);
    }
  }
  // -------- merge (pure sums: no max tracking) --------
  __syncthreads();   // also guards Obuf reuse across phases
  if (wid) {
    float* ob = &Obuf[wid - 1][lane][0];
#pragma unroll
    for (int db = 0; db < 2; ++db)
#pragma unroll
      for (int r = 0; r < 16; ++r)
        ob[db * 16 + r] = O[db][r];
    lbuf[wid - 1][lane] = lacc[0] + lacc[1] + lacc[2] + lacc[3];
  }
  __syncthreads();
  if (wid == 0) {
    float lh = lacc[0] + lacc[1] + lacc[2] + lacc[3];
#pragma unroll
    for (int w = 0; w < 3; ++w) {
      lh += lbuf[w][lane];
      const float* ob = &Obuf[w][lane][0];
#pragma unroll
      for (int db = 0; db < 2; ++db)
#pragma unroll
      for (int r = 0; r < 16; ++r)
          O[db][r] += ob[db * 16 + r];
    }
    unsigned xa = __float_as_uint(lh), xb2 = xa;
    plswap(xa, xb2);                      // xa = [lo|lo], xb2 = [hi|hi]
    const float linv = 1.f / (__uint_as_float(xa) + __uint_as_float(xb2));
    ushort* orow = Oa + ((size_t)(bb * 2048 + q)) * 1024 + h * 64;
#pragma unroll
    for (int db = 0; db < 2; ++db)
#pragma unroll
      for (int rg = 0; rg < 4; ++rg) {
        ushort4 o;
        o.x = f2b(O[db][4 * rg + 0] * linv);
        o.y = f2b(O[db][4 * rg + 1] * linv);
        o.z = f2b(O[db][4 * rg + 2] * linv);
        o.w = f2b(O[db][4 * rg + 3] * linv);
        *reinterpret_cast<ushort4*>(orow + db * 32 + 8 * rg + 4 * hi) = o;
      }
  }
}

// grid: 1024 blocks = (bh, qp); block does q-tiles qp and 63-qp -> constant work.
__global__ __launch_bounds__(256, 2)
void attn_k(const ushort* __restrict__ Qg, const ushort* __restrict__ Kf,
            const ushort* __restrict__ Vf, const float4* __restrict__ relF4,
            ushort* __restrict__ Oa) {
  __shared__ __align__(16) float4 relv4[2048];
  __shared__ float Obuf[3][64][33];
  __shared__ float lbuf[3][64];
  const int f = blockIdx.x;
  const int bh = (f & 7) * 4 + (f >> 8);      // same bh -> same XCD
  const int qp = (f >> 3) & 31;
  const int h = bh & 15, bb = bh >> 4;
  {
    const float4* src = relF4 + (size_t)h * 2048;
    for (int i = threadIdx.x; i < 2048; i += 256)
      relv4[i ^ ((i >> 3) & 3)] = src[i];
  }
  __syncthreads();
  const int wid = threadIdx.x >> 6, lane = threadIdx.x & 63;
  const int li = lane & 31, hi = lane >> 5;
  const ushort* Qb  = Qg + (size_t)bh * (2048 * 64);
  const ushort* Kfb = Kf + (size_t)bh * (32 * 4096);
  const ushort* Vfb = Vf + (size_t)bh * (32 * 4096);
  attn_phase(qp,      wid, lane, li, hi, h, bb, Qb, Kfb, Vfb, relv4, Obuf, lbuf, Oa);
  attn_phase(63 - qp, wid, lane, li, hi, h, bb, Qb, Kfb, Vfb, relv4, Obuf, lbuf, Oa);
}

extern "C" void kernel_launch(void* const* d_in, const int* in_sizes, int n_in,
                              void* d_out, int out_size, void* d_ws, size_t ws_size,
                              hipStream_t stream) {
  const float* x    = (const float*)d_in[0];
  const float* WQ   = (const float*)d_in[1];
  const float* bQ   = (const float*)d_in[2];
  const float* WK   = (const float*)d_in[3];
  const float* bK   = (const float*)d_in[4];
  const float* WV   = (const float*)d_in[5];
  const float* bV   = (const float*)d_in[6];
  const float* WO   = (const float*)d_in[7];
  const float* bO   = (const float*)d_in[8];
  const float* relT = (const float*)d_in[9];
  float* out = (float*)d_out;

  if (ws_size < (size_t)48 * 1024 * 1024) return;

  char* ws = (char*)d_ws;
  const size_t MB = 1024 * 1024;
  ushort* xb    = (ushort*)(ws);             // [4096][1024] bf16; dead after gemm1
  float4* relF4 = (float4*)(ws);             // [16][2048] f32x4 (512KB); overlays xb
  ushort* Wcat  = (ushort*)(ws + 8 * MB);    // [3072][1024] bf16
  ushort* WOb   = (ushort*)(ws + 14 * MB);   // [1024][1024] bf16
  ushort* Qg    = (ushort*)(ws + 16 * MB);   // [2,16,2048,64] bf16
  ushort* Kf    = (ushort*)(ws + 24 * MB);   // K fragment-order (8MB)
  ushort* Vf    = (ushort*)(ws + 32 * MB);   // V fragment-order (8MB)
  ushort* Oa    = (ushort*)(ws + 40 * MB);   // attn out bf16

  prep_cast<<<8192, 256, 0, stream>>>(x, WQ, WK, WV, WO, xb, Wcat, WOb);

  gemm_bt<<<dim3(24, 32), 256, 0, stream>>>(xb, Wcat, bQ, bK, bV, Qg, Kf, Vf);
  prep_f4<<<128, 256, 0, stream>>>(relT, relF4);   // after gemm1: overlays dead xb
  attn_k<<<1024, 256, 0, stream>>>(Qg, Kf, Vf, relF4, Oa);
  gemm_o<<<dim3(8, 64), 256, 0, stream>>>(Oa, WOb, bO, out);
}

// Round 20
// 105.971 us; speedup vs baseline: 1.2233x; 1.0041x over previous
//
#include <hip/hip_runtime.h>
#include <hip/hip_bf16.h>

typedef __attribute__((ext_vector_type(8))) short bf16x8;
typedef __attribute__((ext_vector_type(4))) float f32x4;
typedef __attribute__((ext_vector_type(16))) float f32x16;

#define MFMA16(a, b, c) __builtin_amdgcn_mfma_f32_16x16x32_bf16(a, b, c, 0, 0, 0)
#define MFMA32(a, b, c) __builtin_amdgcn_mfma_f32_32x32x16_bf16(a, b, c, 0, 0, 0)

__device__ inline ushort f2b(float f) {
  union { float f; unsigned u; } v; v.f = f;
  unsigned u = v.u;
  u += 0x7fffu + ((u >> 16) & 1u);   // round-to-nearest-even
  return (ushort)(u >> 16);
}

__device__ inline unsigned cvtpk(float lo, float hi) {
  unsigned r;
  asm("v_cvt_pk_bf16_f32 %0, %1, %2" : "=v"(r) : "v"(lo), "v"(hi));
  return r;
}

// v_permlane32_swap_b32: lanes<32 keep a.lo/get b.lo; lanes>=32 get a.hi/keep b.hi
__device__ inline void plswap(unsigned& a, unsigned& b) {
  asm("v_permlane32_swap_b32 %0, %1" : "+v"(a), "+v"(b));
}

// ---- fused cast: x -> xb, {WQ,WK,WV} -> wcat, WO -> wob ----
__global__ void prep_cast(const float* __restrict__ x,
                          const float* __restrict__ wq, const float* __restrict__ wk,
                          const float* __restrict__ wv, const float* __restrict__ wo,
                          ushort* __restrict__ xb, ushort* __restrict__ wcat,
                          ushort* __restrict__ wob) {
  const int gid = blockIdx.x * 256 + threadIdx.x;
  if (blockIdx.x < 4096) {
    const int i = gid * 4;                     // 4M floats of x
    float4 v = *reinterpret_cast<const float4*>(x + i);
    ushort4 o;
    o.x = f2b(v.x); o.y = f2b(v.y); o.z = f2b(v.z); o.w = f2b(v.w);
    *reinterpret_cast<ushort4*>(xb + i) = o;
  } else {
    const int i = (gid - 4096 * 256) * 4;      // 4M floats of weights
    const int which = i >> 20, off = i & 1048575;
    const float* src = (which == 0) ? wq : (which == 1) ? wk : (which == 2) ? wv : wo;
    float4 v = *reinterpret_cast<const float4*>(src + off);
    ushort4 o;
    o.x = f2b(v.x); o.y = f2b(v.y); o.z = f2b(v.z); o.w = f2b(v.w);
    if (which < 3) *reinterpret_cast<ushort4*>(wcat + i) = o;
    else           *reinterpret_cast<ushort4*>(wob + off) = o;
  }
}

// relF4[h][i] = { b(i), b(i-1), b(i-2), b(i-3) },  b(d) = relT[(d+2047)*16+h]*log2e
__global__ void prep_f4(const float* __restrict__ relT, float4* __restrict__ relF4) {
  const int t = blockIdx.x * 256 + threadIdx.x;   // 16*2048
  const int h = t >> 11, i = t & 2047;
  const float C = 1.4426950408889634f;
  float4 v;
  v.x = relT[(size_t)(i + 2047) * 16 + h] * C;
  v.y = (i >= 1) ? relT[(size_t)(i + 2046) * 16 + h] * C : 0.f;
  v.z = (i >= 2) ? relT[(size_t)(i + 2045) * 16 + h] * C : 0.f;
  v.w = (i >= 3) ? relT[(size_t)(i + 2044) * 16 + h] * C : 0.f;
  relF4[(size_t)h * 2048 + i] = v;
}

// ---------------- GEMM1: QKV projection, 128x128 tile, BK=64, T2 swizzle ----
__global__ __launch_bounds__(256, 3)
void gemm_bt(const ushort* __restrict__ A, const ushort* __restrict__ B,
             const float* __restrict__ b0, const float* __restrict__ b1,
             const float* __restrict__ b2,
             ushort* __restrict__ Qg, ushort* __restrict__ Kf,
             ushort* __restrict__ Vf) {
  __shared__ __align__(16) ushort As[128][64];
  __shared__ __align__(16) ushort Bs[128][64];
  const int tid = threadIdx.x;
  const int m0 = blockIdx.y * 128, n0 = blockIdx.x * 128;
  const int wid = tid >> 6, lane = tid & 63, g = lane >> 4, li = lane & 15;
  const int wr = (wid >> 1) * 64, wc = (wid & 1) * 64;
  const int srow0 = (lane >> 3);
  const int scol = (((lane & 7) ^ (lane >> 3)) * 8);   // pre-swizzled source col
  f32x4 acc[4][4] = {};
  for (int k0 = 0; k0 < 1024; k0 += 64) {
#pragma unroll
    for (int it = 0; it < 4; ++it) {
      const int rb = (wid * 4 + it) * 8;
      __builtin_amdgcn_global_load_lds(
          (const __attribute__((address_space(1))) void*)(A + (size_t)(m0 + rb + srow0) * 1024 + k0 + scol),
          (__attribute__((address_space(3))) void*)(&As[0][0] + (wid * 4 + it) * 512), 16, 0, 0);
      __builtin_amdgcn_global_load_lds(
          (const __attribute__((address_space(1))) void*)(B + (size_t)(n0 + rb + srow0) * 1024 + k0 + scol),
          (__attribute__((address_space(3))) void*)(&Bs[0][0] + (wid * 4 + it) * 512), 16, 0, 0);
    }
    __syncthreads();
#pragma unroll
    for (int kk = 0; kk < 64; kk += 32) {
      bf16x8 af[4], bfm[4];
#pragma unroll
      for (int i = 0; i < 4; ++i) {
        const int cs = (kk + g * 8) ^ ((li & 7) << 3);  // swizzled read col
        af[i]  = *reinterpret_cast<const bf16x8*>(&As[wr + i * 16 + li][cs]);
        bfm[i] = *reinterpret_cast<const bf16x8*>(&Bs[wc + i * 16 + li][cs]);
      }
#pragma unroll
      for (int mi = 0; mi < 4; ++mi)
#pragma unroll
        for (int ni = 0; ni < 4; ++ni)
          acc[mi][ni] = MFMA16(af[mi], bfm[ni], acc[mi][ni]);
    }
    __syncthreads();
  }
#pragma unroll
  for (int mi = 0; mi < 4; ++mi) {
#pragma unroll
    for (int ni = 0; ni < 4; ++ni) {
      const int col = n0 + wc + ni * 16 + li;
      const int which = col >> 10, c = col & 1023;
      const int hh = c >> 6, dk = c & 63;
      const float* bias = (which == 0) ? b0 : ((which == 1) ? b1 : b2);
      const float bcol = bias[c];
      const int row0 = m0 + wr + mi * 16 + 4 * g;
      const int bb = row0 >> 11, t0 = row0 & 2047;  // t0 multiple of 4
      const int bhi = bb * 16 + hh;
      if (which == 0) {
        ushort* dst = Qg + ((size_t)bhi * 2048 + t0) * 64 + dk;
#pragma unroll
        for (int r = 0; r < 4; ++r)
          dst[(size_t)r * 64] = f2b(acc[mi][ni][r] + bcol);
      } else if (which == 1) {
        const size_t cb = ((size_t)((bhi * 32 + (t0 >> 6)) * 8 + ((t0 >> 5) & 1) * 4 + (dk >> 4))) * 512
                          + ((dk >> 3) & 1) * 256 + (dk & 7);
        ushort* dst = Kf + cb + (t0 & 31) * 8;
#pragma unroll
        for (int r = 0; r < 4; ++r)
          dst[r * 8] = f2b(acc[mi][ni][r] + bcol);
      } else {
        const size_t cb = ((size_t)((bhi * 32 + (t0 >> 6)) * 8 + (dk >> 5) * 4 + ((t0 >> 4) & 3))) * 512
                          + (dk & 31) * 8 + ((t0 >> 3) & 1) * 256 + (t0 & 7);
        ushort4 o;
        o.x = f2b(acc[mi][ni][0] + bcol);
        o.y = f2b(acc[mi][ni][1] + bcol);
        o.z = f2b(acc[mi][ni][2] + bcol);
        o.w = f2b(acc[mi][ni][3] + bcol);
        *reinterpret_cast<ushort4*>(Vf + cb) = o;
      }
    }
  }
}

// ---------------- GEMM2: output projection, 64x128 tile (512 blocks = 2/CU) ----
__global__ __launch_bounds__(256, 3)
void gemm_o(const ushort* __restrict__ A, const ushort* __restrict__ B,
            const float* __restrict__ b0, float* __restrict__ outF) {
  __shared__ __align__(16) ushort As[64][64];
  __shared__ __align__(16) ushort Bs[128][64];
  const int tid = threadIdx.x;
  const int m0 = blockIdx.y * 64, n0 = blockIdx.x * 128;
  const int wid = tid >> 6, lane = tid & 63, g = lane >> 4, li = lane & 15;
  const int wr = (wid >> 1) * 32, wc = (wid & 1) * 64;
  const int srow0 = (lane >> 3);
  const int scol = (((lane & 7) ^ (lane >> 3)) * 8);   // pre-swizzled source col
  f32x4 acc[2][4] = {};
  for (int k0 = 0; k0 < 1024; k0 += 64) {
#pragma unroll
    for (int it = 0; it < 2; ++it) {
      const int rb = (wid * 2 + it) * 8;
      __builtin_amdgcn_global_load_lds(
          (const __attribute__((address_space(1))) void*)(A + (size_t)(m0 + rb + srow0) * 1024 + k0 + scol),
          (__attribute__((address_space(3))) void*)(&As[0][0] + (wid * 2 + it) * 512), 16, 0, 0);
    }
#pragma unroll
    for (int it = 0; it < 4; ++it) {
      const int rb = (wid * 4 + it) * 8;
      __builtin_amdgcn_global_load_lds(
          (const __attribute__((address_space(1))) void*)(B + (size_t)(n0 + rb + srow0) * 1024 + k0 + scol),
          (__attribute__((address_space(3))) void*)(&Bs[0][0] + (wid * 4 + it) * 512), 16, 0, 0);
    }
    __syncthreads();
#pragma unroll
    for (int kk = 0; kk < 64; kk += 32) {
      bf16x8 af[2], bfm[4];
      const int cs = (kk + g * 8) ^ ((li & 7) << 3);  // swizzled read col
#pragma unroll
      for (int i = 0; i < 2; ++i)
        af[i] = *reinterpret_cast<const bf16x8*>(&As[wr + i * 16 + li][cs]);
#pragma unroll
      for (int i = 0; i < 4; ++i)
        bfm[i] = *reinterpret_cast<const bf16x8*>(&Bs[wc + i * 16 + li][cs]);
#pragma unroll
      for (int mi = 0; mi < 2; ++mi)
#pragma unroll
        for (int ni = 0; ni < 4; ++ni)
          acc[mi][ni] = MFMA16(af[mi], bfm[ni], acc[mi][ni]);
    }
    __syncthreads();
  }
#pragma unroll
  for (int mi = 0; mi < 2; ++mi) {
#pragma unroll
    for (int ni = 0; ni < 4; ++ni) {
      const int col = n0 + wc + ni * 16 + li;
      const float bcol = b0[col];
#pragma unroll
      for (int r = 0; r < 4; ++r) {
        const int row = m0 + wr + mi * 16 + 4 * g + r;
        outF[(size_t)row * 1024 + col] = acc[mi][ni][r] + bcol;
      }
    }
  }
}

// ---------------- flash attention: fixed-max, split-k x4, F4 bias, T5 setprio ----
__device__ __forceinline__ void attn_phase(
    const int qt, const int wid, const int lane, const int li, const int hi,
    const int h, const int bb,
    const ushort* __restrict__ Qb, const ushort* __restrict__ Kfb,
    const ushort* __restrict__ Vfb, const float4* relv4,
    float Obuf[3][64][33], float lbuf[3][64], ushort* __restrict__ Oa) {
  const int q = qt * 32 + li;
  bf16x8 qf[4];
#pragma unroll
  for (int c = 0; c < 4; ++c)
    qf[c] = *reinterpret_cast<const bf16x8*>(Qb + (size_t)q * 64 + c * 16 + hi * 8);
  f32x16 O[2] = {};
  float lacc[4] = {0.f, 0.f, 0.f, 0.f};
  const int nkt = (qt >> 1) + 1;
  const int nt = (wid < nkt) ? ((nkt - 1 - wid) >> 2) + 1 : 0;
  const int mask_kb = (nkt - 1) * 64;
  const float C1 = 0.18033688f;               // 0.125 * log2(e)
  for (int i = 0; i < nt; ++i) {
    const int kb = wid * 64 + i * 256;
    const ushort* Kt = Kfb + (size_t)(kb >> 6) * 4096 + lane * 8;
    const ushort* Vt = Vfb + (size_t)(kb >> 6) * 4096 + lane * 8;
    bf16x8 Kr[8], Vr[8];
#pragma unroll
    for (int j = 0; j < 8; ++j)
      Kr[j] = *reinterpret_cast<const bf16x8*>(Kt + j * 512);
#pragma unroll
    for (int j = 0; j < 8; ++j)
      Vr[j] = *reinterpret_cast<const bf16x8*>(Vt + j * 512);
    __builtin_amdgcn_sched_barrier(0);
    f32x16 S0 = {}, S1 = {};
    __builtin_amdgcn_s_setprio(1);            // T5: favor MFMA-issuing wave
#pragma unroll
    for (int c = 0; c < 4; ++c) S0 = MFMA32(Kr[c], qf[c], S0);
#pragma unroll
    for (int c = 0; c < 4; ++c) S1 = MFMA32(Kr[4 + c], qf[c], S1);
    __builtin_amdgcn_s_setprio(0);
    const int dqb = q - kb - 4 * hi;
    if (kb != mask_kb) {
#pragma unroll
      for (int rg = 0; rg < 4; ++rg) {
        const int i0 = dqb - 8 * rg, i1 = i0 - 32;
        const float4 bq0 = relv4[i0 ^ ((i0 >> 3) & 3)];
        const float4 bq1 = relv4[i1 ^ ((i1 >> 3) & 3)];
        const float b0e[4] = {bq0.x, bq0.y, bq0.z, bq0.w};
        const float b1e[4] = {bq1.x, bq1.y, bq1.z, bq1.w};
#pragma unroll
        for (int j = 0; j < 4; ++j) {
          const int r = 4 * rg + j;
          const float p0 = __builtin_amdgcn_exp2f(fmaf(S0[r], C1, b0e[j]));
          const float p1 = __builtin_amdgcn_exp2f(fmaf(S1[r], C1, b1e[j]));
          S0[r] = p0; S1[r] = p1;
          lacc[j] += p0 + p1;
        }
      }
    } else {
#pragma unroll
      for (int rg = 0; rg < 4; ++rg) {
        const int d0b = dqb - 8 * rg, d1b = d0b - 32;
        const int i0 = d0b & 2047, i1 = d1b & 2047;
        const float4 bq0 = relv4[i0 ^ ((i0 >> 3) & 3)];
        const float4 bq1 = relv4[i1 ^ ((i1 >> 3) & 3)];
        const float b0e[4] = {bq0.x, bq0.y, bq0.z, bq0.w};
        const float b1e[4] = {bq1.x, bq1.y, bq1.z, bq1.w};
#pragma unroll
        for (int j = 0; j < 4; ++j) {
          const int r = 4 * rg + j;
          float p0 = __builtin_amdgcn_exp2f(fmaf(S0[r], C1, b0e[j]));
          float p1 = __builtin_amdgcn_exp2f(fmaf(S1[r], C1, b1e[j]));
          p0 = (d0b - j >= 0) ? p0 : 0.f;
          p1 = (d1b - j >= 0) ? p1 : 0.f;
          S0[r] = p0; S1[r] = p1;
          lacc[j] += p0 + p1;
        }
      }
    }
    unsigned U0[4][2], U1[4][2];
#pragma unroll
    for (int rg = 0; rg < 4; ++rg) {
      U0[rg][0] = cvtpk(S0[4 * rg + 0], S0[4 * rg + 1]);
      U0[rg][1] = cvtpk(S0[4 * rg + 2], S0[4 * rg + 3]);
      U1[rg][0] = cvtpk(S1[4 * rg + 0], S1[4 * rg + 1]);
      U1[rg][1] = cvtpk(S1[4 * rg + 2], S1[4 * rg + 3]);
    }
    __builtin_amdgcn_s_setprio(1);            // T5: PV MFMA cluster
#pragma unroll
    for (int c = 0; c < 4; ++c) {
      const int c0 = c & 1;
      unsigned x0 = (c < 2) ? U0[2 * c0][0] : U1[2 * c0][0];
      unsigned y0 = (c < 2) ? U0[2 * c0 + 1][0] : U1[2 * c0 + 1][0];
      unsigned x1 = (c < 2) ? U0[2 * c0][1] : U1[2 * c0][1];
      unsigned y1 = (c < 2) ? U0[2 * c0 + 1][1] : U1[2 * c0 + 1][1];
      plswap(x0, y0);
      plswap(x1, y1);
      union { unsigned u[4]; bf16x8 v; } P;
      P.u[0] = x0; P.u[1] = x1; P.u[2] = y0; P.u[3] = y1;
#pragma unroll
      for (int db = 0; db < 2; ++db)
        O[db] = MFMA32(Vr[db * 4 + c], P.v, O[db]);
    }
    __builtin_amdgcn_s_setprio(0);
  }
  // -------- merge (pure sums: no max tracking) --------
  __syncthreads();   // also guards Obuf reuse across phases
  if (wid) {
    float* ob = &Obuf[wid - 1][lane][0];
#pragma unroll
    for (int db = 0; db < 2; ++db)
#pragma unroll
      for (int r = 0; r < 16; ++r)
        ob[db * 16 + r] = O[db][r];
    lbuf[wid - 1][lane] = lacc[0] + lacc[1] + lacc[2] + lacc[3];
  }
  __syncthreads();
  if (wid == 0) {
    float lh = lacc[0] + lacc[1] + lacc[2] + lacc[3];
#pragma unroll
    for (int w = 0; w < 3; ++w) {
      lh += lbuf[w][lane];
      const float* ob = &Obuf[w][lane][0];
#pragma unroll
      for (int db = 0; db < 2; ++db)
#pragma unroll
      for (int r = 0; r < 16; ++r)
          O[db][r] += ob[db * 16 + r];
    }
    unsigned xa = __float_as_uint(lh), xb2 = xa;
    plswap(xa, xb2);                      // xa = [lo|lo], xb2 = [hi|hi]
    const float linv = 1.f / (__uint_as_float(xa) + __uint_as_float(xb2));
    ushort* orow = Oa + ((size_t)(bb * 2048 + q)) * 1024 + h * 64;
#pragma unroll
    for (int db = 0; db < 2; ++db)
#pragma unroll
      for (int rg = 0; rg < 4; ++rg) {
        ushort4 o;
        o.x = f2b(O[db][4 * rg + 0] * linv);
        o.y = f2b(O[db][4 * rg + 1] * linv);
        o.z = f2b(O[db][4 * rg + 2] * linv);
        o.w = f2b(O[db][4 * rg + 3] * linv);
        *reinterpret_cast<ushort4*>(orow + db * 32 + 8 * rg + 4 * hi) = o;
      }
  }
}

// grid: 1024 blocks = (bh, qp); block does q-tiles qp and 63-qp -> constant work.
__global__ __launch_bounds__(256, 2)
void attn_k(const ushort* __restrict__ Qg, const ushort* __restrict__ Kf,
            const ushort* __restrict__ Vf, const float4* __restrict__ relF4,
            ushort* __restrict__ Oa) {
  __shared__ __align__(16) float4 relv4[2048];
  __shared__ float Obuf[3][64][33];
  __shared__ float lbuf[3][64];
  const int f = blockIdx.x;
  const int bh = (f & 7) * 4 + (f >> 8);      // same bh -> same XCD
  const int qp = (f >> 3) & 31;
  const int h = bh & 15, bb = bh >> 4;
  {
    const float4* src = relF4 + (size_t)h * 2048;
    for (int i = threadIdx.x; i < 2048; i += 256)
      relv4[i ^ ((i >> 3) & 3)] = src[i];
  }
  __syncthreads();
  const int wid = threadIdx.x >> 6, lane = threadIdx.x & 63;
  const int li = lane & 31, hi = lane >> 5;
  const ushort* Qb  = Qg + (size_t)bh * (2048 * 64);
  const ushort* Kfb = Kf + (size_t)bh * (32 * 4096);
  const ushort* Vfb = Vf + (size_t)bh * (32 * 4096);
  attn_phase(qp,      wid, lane, li, hi, h, bb, Qb, Kfb, Vfb, relv4, Obuf, lbuf, Oa);
  attn_phase(63 - qp, wid, lane, li, hi, h, bb, Qb, Kfb, Vfb, relv4, Obuf, lbuf, Oa);
}

extern "C" void kernel_launch(void* const* d_in, const int* in_sizes, int n_in,
                              void* d_out, int out_size, void* d_ws, size_t ws_size,
                              hipStream_t stream) {
  const float* x    = (const float*)d_in[0];
  const float* WQ   = (const float*)d_in[1];
  const float* bQ   = (const float*)d_in[2];
  const float* WK   = (const float*)d_in[3];
  const float* bK   = (const float*)d_in[4];
  const float* WV   = (const float*)d_in[5];
  const float* bV   = (const float*)d_in[6];
  const float* WO   = (const float*)d_in[7];
  const float* bO   = (const float*)d_in[8];
  const float* relT = (const float*)d_in[9];
  float* out = (float*)d_out;

  if (ws_size < (size_t)48 * 1024 * 1024) return;

  char* ws = (char*)d_ws;
  const size_t MB = 1024 * 1024;
  ushort* xb    = (ushort*)(ws);             // [4096][1024] bf16; dead after gemm1
  float4* relF4 = (float4*)(ws);             // [16][2048] f32x4 (512KB); overlays xb
  ushort* Wcat  = (ushort*)(ws + 8 * MB);    // [3072][1024] bf16
  ushort* WOb   = (ushort*)(ws + 14 * MB);   // [1024][1024] bf16
  ushort* Qg    = (ushort*)(ws + 16 * MB);   // [2,16,2048,64] bf16
  ushort* Kf    = (ushort*)(ws + 24 * MB);   // K fragment-order (8MB)
  ushort* Vf    = (ushort*)(ws + 32 * MB);   // V fragment-order (8MB)
  ushort* Oa    = (ushort*)(ws + 40 * MB);   // attn out bf16

  prep_cast<<<8192, 256, 0, stream>>>(x, WQ, WK, WV, WO, xb, Wcat, WOb);

  gemm_bt<<<dim3(24, 32), 256, 0, stream>>>(xb, Wcat, bQ, bK, bV, Qg, Kf, Vf);
  prep_f4<<<128, 256, 0, stream>>>(relT, relF4);   // after gemm1: overlays dead xb
  attn_k<<<1024, 256, 0, stream>>>(Qg, Kf, Vf, relF4, Oa);
  gemm_o<<<dim3(8, 64), 256, 0, stream>>>(Oa, WOb, bO, out);
}

// Round 21
// 104.969 us; speedup vs baseline: 1.2350x; 1.0095x over previous
//
#include <hip/hip_runtime.h>
#include <hip/hip_bf16.h>

typedef __attribute__((ext_vector_type(8))) short bf16x8;
typedef __attribute__((ext_vector_type(4))) float f32x4;
typedef __attribute__((ext_vector_type(16))) float f32x16;

#define MFMA16(a, b, c) __builtin_amdgcn_mfma_f32_16x16x32_bf16(a, b, c, 0, 0, 0)
#define MFMA32(a, b, c) __builtin_amdgcn_mfma_f32_32x32x16_bf16(a, b, c, 0, 0, 0)

__device__ inline ushort f2b(float f) {
  union { float f; unsigned u; } v; v.f = f;
  unsigned u = v.u;
  u += 0x7fffu + ((u >> 16) & 1u);   // round-to-nearest-even
  return (ushort)(u >> 16);
}

__device__ inline unsigned cvtpk(float lo, float hi) {
  unsigned r;
  asm("v_cvt_pk_bf16_f32 %0, %1, %2" : "=v"(r) : "v"(lo), "v"(hi));
  return r;
}

// v_permlane32_swap_b32: lanes<32 keep a.lo/get b.lo; lanes>=32 get a.hi/keep b.hi
__device__ inline void plswap(unsigned& a, unsigned& b) {
  asm("v_permlane32_swap_b32 %0, %1" : "+v"(a), "+v"(b));
}

// ---- fused prep: x -> xb, {WQ,WK,WV} -> wcat, WO -> wob, relT -> relF4 ----
// relF4 lives at ws+40MB (disjoint from xb/wcat/wob) -> safe to fuse here.
__global__ void prep_cast(const float* __restrict__ x,
                          const float* __restrict__ wq, const float* __restrict__ wk,
                          const float* __restrict__ wv, const float* __restrict__ wo,
                          const float* __restrict__ relT,
                          ushort* __restrict__ xb, ushort* __restrict__ wcat,
                          ushort* __restrict__ wob, float4* __restrict__ relF4) {
  const int gid = blockIdx.x * 256 + threadIdx.x;
  if (blockIdx.x < 4096) {
    const int i = gid * 4;                     // 4M floats of x
    float4 v = *reinterpret_cast<const float4*>(x + i);
    ushort4 o;
    o.x = f2b(v.x); o.y = f2b(v.y); o.z = f2b(v.z); o.w = f2b(v.w);
    *reinterpret_cast<ushort4*>(xb + i) = o;
  } else if (blockIdx.x < 8192) {
    const int i = (gid - 4096 * 256) * 4;      // 4M floats of weights
    const int which = i >> 20, off = i & 1048575;
    const float* src = (which == 0) ? wq : (which == 1) ? wk : (which == 2) ? wv : wo;
    float4 v = *reinterpret_cast<const float4*>(src + off);
    ushort4 o;
    o.x = f2b(v.x); o.y = f2b(v.y); o.z = f2b(v.z); o.w = f2b(v.w);
    if (which < 3) *reinterpret_cast<ushort4*>(wcat + i) = o;
    else           *reinterpret_cast<ushort4*>(wob + off) = o;
  } else {
    const int t = gid - 8192 * 256;            // 16*2048 rel entries
    const int h = t >> 11, i = t & 2047;
    const float C = 1.4426950408889634f;
    float4 v;
    v.x = relT[(size_t)(i + 2047) * 16 + h] * C;
    v.y = (i >= 1) ? relT[(size_t)(i + 2046) * 16 + h] * C : 0.f;
    v.z = (i >= 2) ? relT[(size_t)(i + 2045) * 16 + h] * C : 0.f;
    v.w = (i >= 3) ? relT[(size_t)(i + 2044) * 16 + h] * C : 0.f;
    relF4[(size_t)h * 2048 + i] = v;
  }
}

// ---------------- GEMM1: QKV projection, 128x128 tile, BK=64, T2 swizzle ----
__global__ __launch_bounds__(256, 3)
void gemm_bt(const ushort* __restrict__ A, const ushort* __restrict__ B,
             const float* __restrict__ b0, const float* __restrict__ b1,
             const float* __restrict__ b2,
             ushort* __restrict__ Qg, ushort* __restrict__ Kf,
             ushort* __restrict__ Vf) {
  __shared__ __align__(16) ushort As[128][64];
  __shared__ __align__(16) ushort Bs[128][64];
  const int tid = threadIdx.x;
  const int m0 = blockIdx.y * 128, n0 = blockIdx.x * 128;
  const int wid = tid >> 6, lane = tid & 63, g = lane >> 4, li = lane & 15;
  const int wr = (wid >> 1) * 64, wc = (wid & 1) * 64;
  const int srow0 = (lane >> 3);
  const int scol = (((lane & 7) ^ (lane >> 3)) * 8);   // pre-swizzled source col
  f32x4 acc[4][4] = {};
  for (int k0 = 0; k0 < 1024; k0 += 64) {
#pragma unroll
    for (int it = 0; it < 4; ++it) {
      const int rb = (wid * 4 + it) * 8;
      __builtin_amdgcn_global_load_lds(
          (const __attribute__((address_space(1))) void*)(A + (size_t)(m0 + rb + srow0) * 1024 + k0 + scol),
          (__attribute__((address_space(3))) void*)(&As[0][0] + (wid * 4 + it) * 512), 16, 0, 0);
      __builtin_amdgcn_global_load_lds(
          (const __attribute__((address_space(1))) void*)(B + (size_t)(n0 + rb + srow0) * 1024 + k0 + scol),
          (__attribute__((address_space(3))) void*)(&Bs[0][0] + (wid * 4 + it) * 512), 16, 0, 0);
    }
    __syncthreads();
#pragma unroll
    for (int kk = 0; kk < 64; kk += 32) {
      bf16x8 af[4], bfm[4];
#pragma unroll
      for (int i = 0; i < 4; ++i) {
        const int cs = (kk + g * 8) ^ ((li & 7) << 3);  // swizzled read col
        af[i]  = *reinterpret_cast<const bf16x8*>(&As[wr + i * 16 + li][cs]);
        bfm[i] = *reinterpret_cast<const bf16x8*>(&Bs[wc + i * 16 + li][cs]);
      }
#pragma unroll
      for (int mi = 0; mi < 4; ++mi)
#pragma unroll
        for (int ni = 0; ni < 4; ++ni)
          acc[mi][ni] = MFMA16(af[mi], bfm[ni], acc[mi][ni]);
    }
    __syncthreads();
  }
#pragma unroll
  for (int mi = 0; mi < 4; ++mi) {
#pragma unroll
    for (int ni = 0; ni < 4; ++ni) {
      const int col = n0 + wc + ni * 16 + li;
      const int which = col >> 10, c = col & 1023;
      const int hh = c >> 6, dk = c & 63;
      const float* bias = (which == 0) ? b0 : ((which == 1) ? b1 : b2);
      const float bcol = bias[c];
      const int row0 = m0 + wr + mi * 16 + 4 * g;
      const int bb = row0 >> 11, t0 = row0 & 2047;  // t0 multiple of 4
      const int bhi = bb * 16 + hh;
      if (which == 0) {
        ushort* dst = Qg + ((size_t)bhi * 2048 + t0) * 64 + dk;
#pragma unroll
        for (int r = 0; r < 4; ++r)
          dst[(size_t)r * 64] = f2b(acc[mi][ni][r] + bcol);
      } else if (which == 1) {
        const size_t cb = ((size_t)((bhi * 32 + (t0 >> 6)) * 8 + ((t0 >> 5) & 1) * 4 + (dk >> 4))) * 512
                          + ((dk >> 3) & 1) * 256 + (dk & 7);
        ushort* dst = Kf + cb + (t0 & 31) * 8;
#pragma unroll
        for (int r = 0; r < 4; ++r)
          dst[r * 8] = f2b(acc[mi][ni][r] + bcol);
      } else {
        const size_t cb = ((size_t)((bhi * 32 + (t0 >> 6)) * 8 + (dk >> 5) * 4 + ((t0 >> 4) & 3))) * 512
                          + (dk & 31) * 8 + ((t0 >> 3) & 1) * 256 + (t0 & 7);
        ushort4 o;
        o.x = f2b(acc[mi][ni][0] + bcol);
        o.y = f2b(acc[mi][ni][1] + bcol);
        o.z = f2b(acc[mi][ni][2] + bcol);
        o.w = f2b(acc[mi][ni][3] + bcol);
        *reinterpret_cast<ushort4*>(Vf + cb) = o;
      }
    }
  }
}

// ---------------- GEMM2: output projection, 64x128 tile (512 blocks = 2/CU) ----
__global__ __launch_bounds__(256, 3)
void gemm_o(const ushort* __restrict__ A, const ushort* __restrict__ B,
            const float* __restrict__ b0, float* __restrict__ outF) {
  __shared__ __align__(16) ushort As[64][64];
  __shared__ __align__(16) ushort Bs[128][64];
  const int tid = threadIdx.x;
  const int m0 = blockIdx.y * 64, n0 = blockIdx.x * 128;
  const int wid = tid >> 6, lane = tid & 63, g = lane >> 4, li = lane & 15;
  const int wr = (wid >> 1) * 32, wc = (wid & 1) * 64;
  const int srow0 = (lane >> 3);
  const int scol = (((lane & 7) ^ (lane >> 3)) * 8);   // pre-swizzled source col
  f32x4 acc[2][4] = {};
  for (int k0 = 0; k0 < 1024; k0 += 64) {
#pragma unroll
    for (int it = 0; it < 2; ++it) {
      const int rb = (wid * 2 + it) * 8;
      __builtin_amdgcn_global_load_lds(
          (const __attribute__((address_space(1))) void*)(A + (size_t)(m0 + rb + srow0) * 1024 + k0 + scol),
          (__attribute__((address_space(3))) void*)(&As[0][0] + (wid * 2 + it) * 512), 16, 0, 0);
    }
#pragma unroll
    for (int it = 0; it < 4; ++it) {
      const int rb = (wid * 4 + it) * 8;
      __builtin_amdgcn_global_load_lds(
          (const __attribute__((address_space(1))) void*)(B + (size_t)(n0 + rb + srow0) * 1024 + k0 + scol),
          (__attribute__((address_space(3))) void*)(&Bs[0][0] + (wid * 4 + it) * 512), 16, 0, 0);
    }
    __syncthreads();
#pragma unroll
    for (int kk = 0; kk < 64; kk += 32) {
      bf16x8 af[2], bfm[4];
      const int cs = (kk + g * 8) ^ ((li & 7) << 3);  // swizzled read col
#pragma unroll
      for (int i = 0; i < 2; ++i)
        af[i] = *reinterpret_cast<const bf16x8*>(&As[wr + i * 16 + li][cs]);
#pragma unroll
      for (int i = 0; i < 4; ++i)
        bfm[i] = *reinterpret_cast<const bf16x8*>(&Bs[wc + i * 16 + li][cs]);
#pragma unroll
      for (int mi = 0; mi < 2; ++mi)
#pragma unroll
        for (int ni = 0; ni < 4; ++ni)
          acc[mi][ni] = MFMA16(af[mi], bfm[ni], acc[mi][ni]);
    }
    __syncthreads();
  }
#pragma unroll
  for (int mi = 0; mi < 2; ++mi) {
#pragma unroll
    for (int ni = 0; ni < 4; ++ni) {
      const int col = n0 + wc + ni * 16 + li;
      const float bcol = b0[col];
#pragma unroll
      for (int r = 0; r < 4; ++r) {
        const int row = m0 + wr + mi * 16 + 4 * g + r;
        outF[(size_t)row * 1024 + col] = acc[mi][ni][r] + bcol;
      }
    }
  }
}

// ---------------- flash attention: fixed-max, split-k x4, F4 vectorized bias ----
// (R14/R18/R19 kernel verbatim — best measured config: 41.4 us, VGPR 92.)
__device__ __forceinline__ void attn_phase(
    const int qt, const int wid, const int lane, const int li, const int hi,
    const int h, const int bb,
    const ushort* __restrict__ Qb, const ushort* __restrict__ Kfb,
    const ushort* __restrict__ Vfb, const float4* relv4,
    float Obuf[3][64][33], float lbuf[3][64], ushort* __restrict__ Oa) {
  const int q = qt * 32 + li;
  bf16x8 qf[4];
#pragma unroll
  for (int c = 0; c < 4; ++c)
    qf[c] = *reinterpret_cast<const bf16x8*>(Qb + (size_t)q * 64 + c * 16 + hi * 8);
  f32x16 O[2] = {};
  float lacc[4] = {0.f, 0.f, 0.f, 0.f};
  const int nkt = (qt >> 1) + 1;
  const int nt = (wid < nkt) ? ((nkt - 1 - wid) >> 2) + 1 : 0;
  const int mask_kb = (nkt - 1) * 64;
  const float C1 = 0.18033688f;               // 0.125 * log2(e)
  for (int i = 0; i < nt; ++i) {
    const int kb = wid * 64 + i * 256;
    const ushort* Kt = Kfb + (size_t)(kb >> 6) * 4096 + lane * 8;
    const ushort* Vt = Vfb + (size_t)(kb >> 6) * 4096 + lane * 8;
    bf16x8 Kr[8], Vr[8];
#pragma unroll
    for (int j = 0; j < 8; ++j)
      Kr[j] = *reinterpret_cast<const bf16x8*>(Kt + j * 512);
#pragma unroll
    for (int j = 0; j < 8; ++j)
      Vr[j] = *reinterpret_cast<const bf16x8*>(Vt + j * 512);
    __builtin_amdgcn_sched_barrier(0);
    f32x16 S0 = {}, S1 = {};
#pragma unroll
    for (int c = 0; c < 4; ++c) S0 = MFMA32(Kr[c], qf[c], S0);
#pragma unroll
    for (int c = 0; c < 4; ++c) S1 = MFMA32(Kr[4 + c], qf[c], S1);
    const int dqb = q - kb - 4 * hi;
    if (kb != mask_kb) {
#pragma unroll
      for (int rg = 0; rg < 4; ++rg) {
        const int i0 = dqb - 8 * rg, i1 = i0 - 32;
        const float4 bq0 = relv4[i0 ^ ((i0 >> 3) & 3)];
        const float4 bq1 = relv4[i1 ^ ((i1 >> 3) & 3)];
        const float b0e[4] = {bq0.x, bq0.y, bq0.z, bq0.w};
        const float b1e[4] = {bq1.x, bq1.y, bq1.z, bq1.w};
#pragma unroll
        for (int j = 0; j < 4; ++j) {
          const int r = 4 * rg + j;
          const float p0 = __builtin_amdgcn_exp2f(fmaf(S0[r], C1, b0e[j]));
          const float p1 = __builtin_amdgcn_exp2f(fmaf(S1[r], C1, b1e[j]));
          S0[r] = p0; S1[r] = p1;
          lacc[j] += p0 + p1;
        }
      }
    } else {
#pragma unroll
      for (int rg = 0; rg < 4; ++rg) {
        const int d0b = dqb - 8 * rg, d1b = d0b - 32;
        const int i0 = d0b & 2047, i1 = d1b & 2047;
        const float4 bq0 = relv4[i0 ^ ((i0 >> 3) & 3)];
        const float4 bq1 = relv4[i1 ^ ((i1 >> 3) & 3)];
        const float b0e[4] = {bq0.x, bq0.y, bq0.z, bq0.w};
        const float b1e[4] = {bq1.x, bq1.y, bq1.z, bq1.w};
#pragma unroll
        for (int j = 0; j < 4; ++j) {
          const int r = 4 * rg + j;
          float p0 = __builtin_amdgcn_exp2f(fmaf(S0[r], C1, b0e[j]));
          float p1 = __builtin_amdgcn_exp2f(fmaf(S1[r], C1, b1e[j]));
          p0 = (d0b - j >= 0) ? p0 : 0.f;
          p1 = (d1b - j >= 0) ? p1 : 0.f;
          S0[r] = p0; S1[r] = p1;
          lacc[j] += p0 + p1;
        }
      }
    }
    unsigned U0[4][2], U1[4][2];
#pragma unroll
    for (int rg = 0; rg < 4; ++rg) {
      U0[rg][0] = cvtpk(S0[4 * rg + 0], S0[4 * rg + 1]);
      U0[rg][1] = cvtpk(S0[4 * rg + 2], S0[4 * rg + 3]);
      U1[rg][0] = cvtpk(S1[4 * rg + 0], S1[4 * rg + 1]);
      U1[rg][1] = cvtpk(S1[4 * rg + 2], S1[4 * rg + 3]);
    }
#pragma unroll
    for (int c = 0; c < 4; ++c) {
      const int c0 = c & 1;
      unsigned x0 = (c < 2) ? U0[2 * c0][0] : U1[2 * c0][0];
      unsigned y0 = (c < 2) ? U0[2 * c0 + 1][0] : U1[2 * c0 + 1][0];
      unsigned x1 = (c < 2) ? U0[2 * c0][1] : U1[2 * c0][1];
      unsigned y1 = (c < 2) ? U0[2 * c0 + 1][1] : U1[2 * c0 + 1][1];
      plswap(x0, y0);
      plswap(x1, y1);
      union { unsigned u[4]; bf16x8 v; } P;
      P.u[0] = x0; P.u[1] = x1; P.u[2] = y0; P.u[3] = y1;
#pragma unroll
      for (int db = 0; db < 2; ++db)
        O[db] = MFMA32(Vr[db * 4 + c], P.v, O[db]);
    }
  }
  // -------- merge (pure sums: no max tracking) --------
  __syncthreads();   // also guards Obuf reuse across phases
  if (wid) {
    float* ob = &Obuf[wid - 1][lane][0];
#pragma unroll
    for (int db = 0; db < 2; ++db)
#pragma unroll
      for (int r = 0; r < 16; ++r)
        ob[db * 16 + r] = O[db][r];
    lbuf[wid - 1][lane] = lacc[0] + lacc[1] + lacc[2] + lacc[3];
  }
  __syncthreads();
  if (wid == 0) {
    float lh = lacc[0] + lacc[1] + lacc[2] + lacc[3];
#pragma unroll
    for (int w = 0; w < 3; ++w) {
      lh += lbuf[w][lane];
      const float* ob = &Obuf[w][lane][0];
#pragma unroll
      for (int db = 0; db < 2; ++db)
#pragma unroll
      for (int r = 0; r < 16; ++r)
          O[db][r] += ob[db * 16 + r];
    }
    unsigned xa = __float_as_uint(lh), xb2 = xa;
    plswap(xa, xb2);                      // xa = [lo|lo], xb2 = [hi|hi]
    const float linv = 1.f / (__uint_as_float(xa) + __uint_as_float(xb2));
    ushort* orow = Oa + ((size_t)(bb * 2048 + q)) * 1024 + h * 64;
#pragma unroll
    for (int db = 0; db < 2; ++db)
#pragma unroll
      for (int rg = 0; rg < 4; ++rg) {
        ushort4 o;
        o.x = f2b(O[db][4 * rg + 0] * linv);
        o.y = f2b(O[db][4 * rg + 1] * linv);
        o.z = f2b(O[db][4 * rg + 2] * linv);
        o.w = f2b(O[db][4 * rg + 3] * linv);
        *reinterpret_cast<ushort4*>(orow + db * 32 + 8 * rg + 4 * hi) = o;
      }
  }
}

// grid: 1024 blocks = (bh, qp); block does q-tiles qp and 63-qp -> constant work.
__global__ __launch_bounds__(256, 2)
void attn_k(const ushort* __restrict__ Qg, const ushort* __restrict__ Kf,
            const ushort* __restrict__ Vf, const float4* __restrict__ relF4,
            ushort* __restrict__ Oa) {
  __shared__ __align__(16) float4 relv4[2048];
  __shared__ float Obuf[3][64][33];
  __shared__ float lbuf[3][64];
  const int f = blockIdx.x;
  const int bh = (f & 7) * 4 + (f >> 8);      // same bh -> same XCD
  const int qp = (f >> 3) & 31;
  const int h = bh & 15, bb = bh >> 4;
  {
    const float4* src = relF4 + (size_t)h * 2048;
    for (int i = threadIdx.x; i < 2048; i += 256)
      relv4[i ^ ((i >> 3) & 3)] = src[i];
  }
  __syncthreads();
  const int wid = threadIdx.x >> 6, lane = threadIdx.x & 63;
  const int li = lane & 31, hi = lane >> 5;
  const ushort* Qb  = Qg + (size_t)bh * (2048 * 64);
  const ushort* Kfb = Kf + (size_t)bh * (32 * 4096);
  const ushort* Vfb = Vf + (size_t)bh * (32 * 4096);
  attn_phase(qp,      wid, lane, li, hi, h, bb, Qb, Kfb, Vfb, relv4, Obuf, lbuf, Oa);
  attn_phase(63 - qp, wid, lane, li, hi, h, bb, Qb, Kfb, Vfb, relv4, Obuf, lbuf, Oa);
}

extern "C" void kernel_launch(void* const* d_in, const int* in_sizes, int n_in,
                              void* d_out, int out_size, void* d_ws, size_t ws_size,
                              hipStream_t stream) {
  const float* x    = (const float*)d_in[0];
  const float* WQ   = (const float*)d_in[1];
  const float* bQ   = (const float*)d_in[2];
  const float* WK   = (const float*)d_in[3];
  const float* bK   = (const float*)d_in[4];
  const float* WV   = (const float*)d_in[5];
  const float* bV   = (const float*)d_in[6];
  const float* WO   = (const float*)d_in[7];
  const float* bO   = (const float*)d_in[8];
  const float* relT = (const float*)d_in[9];
  float* out = (float*)d_out;

  if (ws_size < (size_t)48 * 1024 * 1024) return;

  char* ws = (char*)d_ws;
  const size_t MB = 1024 * 1024;
  // timeline: xb (0-8M) dead after gemm1 -> Oa reuses it; relF4 at 40M (was Oa).
  ushort* xb    = (ushort*)(ws);             // [4096][1024] bf16; dead after gemm1
  ushort* Oa    = (ushort*)(ws);             // attn out bf16, overlays dead xb
  ushort* Wcat  = (ushort*)(ws + 8 * MB);    // [3072][1024] bf16
  ushort* WOb   = (ushort*)(ws + 14 * MB);   // [1024][1024] bf16
  ushort* Qg    = (ushort*)(ws + 16 * MB);   // [2,16,2048,64] bf16
  ushort* Kf    = (ushort*)(ws + 24 * MB);   // K fragment-order (8MB)
  ushort* Vf    = (ushort*)(ws + 32 * MB);   // V fragment-order (8MB)
  float4* relF4 = (float4*)(ws + 40 * MB);   // [16][2048] f32x4 (512KB)

  prep_cast<<<8320, 256, 0, stream>>>(x, WQ, WK, WV, WO, relT, xb, Wcat, WOb, relF4);
  gemm_bt<<<dim3(24, 32), 256, 0, stream>>>(xb, Wcat, bQ, bK, bV, Qg, Kf, Vf);
  attn_k<<<1024, 256, 0, stream>>>(Qg, Kf, Vf, relF4, Oa);
  gemm_o<<<dim3(8, 64), 256, 0, stream>>>(Oa, WOb, bO, out);
}

// Round 22
// 104.395 us; speedup vs baseline: 1.2418x; 1.0055x over previous
//
#include <hip/hip_runtime.h>
#include <hip/hip_bf16.h>

typedef __attribute__((ext_vector_type(8))) short bf16x8;
typedef __attribute__((ext_vector_type(4))) float f32x4;
typedef __attribute__((ext_vector_type(16))) float f32x16;

#define MFMA16(a, b, c) __builtin_amdgcn_mfma_f32_16x16x32_bf16(a, b, c, 0, 0, 0)
#define MFMA32(a, b, c) __builtin_amdgcn_mfma_f32_32x32x16_bf16(a, b, c, 0, 0, 0)

__device__ inline ushort f2b(float f) {
  union { float f; unsigned u; } v; v.f = f;
  unsigned u = v.u;
  u += 0x7fffu + ((u >> 16) & 1u);   // round-to-nearest-even
  return (ushort)(u >> 16);
}

__device__ inline unsigned cvtpk(float lo, float hi) {
  unsigned r;
  asm("v_cvt_pk_bf16_f32 %0, %1, %2" : "=v"(r) : "v"(lo), "v"(hi));
  return r;
}

// v_permlane32_swap_b32: lanes<32 keep a.lo/get b.lo; lanes>=32 get a.hi/keep b.hi
__device__ inline void plswap(unsigned& a, unsigned& b) {
  asm("v_permlane32_swap_b32 %0, %1" : "+v"(a), "+v"(b));
}

// ---- fused prep: x -> xb, {WQ,WK,WV} -> wcat, WO -> wob, relT -> relF4 ----
// relF4 lives at ws+40MB (disjoint from xb/wcat/wob) -> safe to fuse here.
__global__ void prep_cast(const float* __restrict__ x,
                          const float* __restrict__ wq, const float* __restrict__ wk,
                          const float* __restrict__ wv, const float* __restrict__ wo,
                          const float* __restrict__ relT,
                          ushort* __restrict__ xb, ushort* __restrict__ wcat,
                          ushort* __restrict__ wob, float4* __restrict__ relF4) {
  const int gid = blockIdx.x * 256 + threadIdx.x;
  if (blockIdx.x < 4096) {
    const int i = gid * 4;                     // 4M floats of x
    float4 v = *reinterpret_cast<const float4*>(x + i);
    ushort4 o;
    o.x = f2b(v.x); o.y = f2b(v.y); o.z = f2b(v.z); o.w = f2b(v.w);
    *reinterpret_cast<ushort4*>(xb + i) = o;
  } else if (blockIdx.x < 8192) {
    const int i = (gid - 4096 * 256) * 4;      // 4M floats of weights
    const int which = i >> 20, off = i & 1048575;
    const float* src = (which == 0) ? wq : (which == 1) ? wk : (which == 2) ? wv : wo;
    float4 v = *reinterpret_cast<const float4*>(src + off);
    ushort4 o;
    o.x = f2b(v.x); o.y = f2b(v.y); o.z = f2b(v.z); o.w = f2b(v.w);
    if (which < 3) *reinterpret_cast<ushort4*>(wcat + i) = o;
    else           *reinterpret_cast<ushort4*>(wob + off) = o;
  } else {
    const int t = gid - 8192 * 256;            // 16*2048 rel entries
    const int h = t >> 11, i = t & 2047;
    const float C = 1.4426950408889634f;
    float4 v;
    v.x = relT[(size_t)(i + 2047) * 16 + h] * C;
    v.y = (i >= 1) ? relT[(size_t)(i + 2046) * 16 + h] * C : 0.f;
    v.z = (i >= 2) ? relT[(size_t)(i + 2045) * 16 + h] * C : 0.f;
    v.w = (i >= 3) ? relT[(size_t)(i + 2044) * 16 + h] * C : 0.f;
    relF4[(size_t)h * 2048 + i] = v;
  }
}

// ---------------- GEMM1: QKV projection, 128x128 tile, BK=64, T2 swizzle ----
__global__ __launch_bounds__(256, 3)
void gemm_bt(const ushort* __restrict__ A, const ushort* __restrict__ B,
             const float* __restrict__ b0, const float* __restrict__ b1,
             const float* __restrict__ b2,
             ushort* __restrict__ Qg, ushort* __restrict__ Kf,
             ushort* __restrict__ Vf) {
  __shared__ __align__(16) ushort As[128][64];
  __shared__ __align__(16) ushort Bs[128][64];
  const int tid = threadIdx.x;
  const int m0 = blockIdx.y * 128, n0 = blockIdx.x * 128;
  const int wid = tid >> 6, lane = tid & 63, g = lane >> 4, li = lane & 15;
  const int wr = (wid >> 1) * 64, wc = (wid & 1) * 64;
  const int srow0 = (lane >> 3);
  const int scol = (((lane & 7) ^ (lane >> 3)) * 8);   // pre-swizzled source col
  f32x4 acc[4][4] = {};
  for (int k0 = 0; k0 < 1024; k0 += 64) {
#pragma unroll
    for (int it = 0; it < 4; ++it) {
      const int rb = (wid * 4 + it) * 8;
      __builtin_amdgcn_global_load_lds(
          (const __attribute__((address_space(1))) void*)(A + (size_t)(m0 + rb + srow0) * 1024 + k0 + scol),
          (__attribute__((address_space(3))) void*)(&As[0][0] + (wid * 4 + it) * 512), 16, 0, 0);
      __builtin_amdgcn_global_load_lds(
          (const __attribute__((address_space(1))) void*)(B + (size_t)(n0 + rb + srow0) * 1024 + k0 + scol),
          (__attribute__((address_space(3))) void*)(&Bs[0][0] + (wid * 4 + it) * 512), 16, 0, 0);
    }
    __syncthreads();
#pragma unroll
    for (int kk = 0; kk < 64; kk += 32) {
      bf16x8 af[4], bfm[4];
#pragma unroll
      for (int i = 0; i < 4; ++i) {
        const int cs = (kk + g * 8) ^ ((li & 7) << 3);  // swizzled read col
        af[i]  = *reinterpret_cast<const bf16x8*>(&As[wr + i * 16 + li][cs]);
        bfm[i] = *reinterpret_cast<const bf16x8*>(&Bs[wc + i * 16 + li][cs]);
      }
#pragma unroll
      for (int mi = 0; mi < 4; ++mi)
#pragma unroll
        for (int ni = 0; ni < 4; ++ni)
          acc[mi][ni] = MFMA16(af[mi], bfm[ni], acc[mi][ni]);
    }
    __syncthreads();
  }
#pragma unroll
  for (int mi = 0; mi < 4; ++mi) {
#pragma unroll
    for (int ni = 0; ni < 4; ++ni) {
      const int col = n0 + wc + ni * 16 + li;
      const int which = col >> 10, c = col & 1023;
      const int hh = c >> 6, dk = c & 63;
      const float* bias = (which == 0) ? b0 : ((which == 1) ? b1 : b2);
      const float bcol = bias[c];
      const int row0 = m0 + wr + mi * 16 + 4 * g;
      const int bb = row0 >> 11, t0 = row0 & 2047;  // t0 multiple of 4
      const int bhi = bb * 16 + hh;
      if (which == 0) {
        ushort* dst = Qg + ((size_t)bhi * 2048 + t0) * 64 + dk;
#pragma unroll
        for (int r = 0; r < 4; ++r)
          dst[(size_t)r * 64] = f2b(acc[mi][ni][r] + bcol);
      } else if (which == 1) {
        const size_t cb = ((size_t)((bhi * 32 + (t0 >> 6)) * 8 + ((t0 >> 5) & 1) * 4 + (dk >> 4))) * 512
                          + ((dk >> 3) & 1) * 256 + (dk & 7);
        ushort* dst = Kf + cb + (t0 & 31) * 8;
#pragma unroll
        for (int r = 0; r < 4; ++r)
          dst[r * 8] = f2b(acc[mi][ni][r] + bcol);
      } else {
        const size_t cb = ((size_t)((bhi * 32 + (t0 >> 6)) * 8 + (dk >> 5) * 4 + ((t0 >> 4) & 3))) * 512
                          + (dk & 31) * 8 + ((t0 >> 3) & 1) * 256 + (t0 & 7);
        ushort4 o;
        o.x = f2b(acc[mi][ni][0] + bcol);
        o.y = f2b(acc[mi][ni][1] + bcol);
        o.z = f2b(acc[mi][ni][2] + bcol);
        o.w = f2b(acc[mi][ni][3] + bcol);
        *reinterpret_cast<ushort4*>(Vf + cb) = o;
      }
    }
  }
}

// ---------------- GEMM2: output projection, 64x128 tile (512 blocks = 2/CU) ----
__global__ __launch_bounds__(256, 3)
void gemm_o(const ushort* __restrict__ A, const ushort* __restrict__ B,
            const float* __restrict__ b0, float* __restrict__ outF) {
  __shared__ __align__(16) ushort As[64][64];
  __shared__ __align__(16) ushort Bs[128][64];
  const int tid = threadIdx.x;
  const int m0 = blockIdx.y * 64, n0 = blockIdx.x * 128;
  const int wid = tid >> 6, lane = tid & 63, g = lane >> 4, li = lane & 15;
  const int wr = (wid >> 1) * 32, wc = (wid & 1) * 64;
  const int srow0 = (lane >> 3);
  const int scol = (((lane & 7) ^ (lane >> 3)) * 8);   // pre-swizzled source col
  f32x4 acc[2][4] = {};
  for (int k0 = 0; k0 < 1024; k0 += 64) {
#pragma unroll
    for (int it = 0; it < 2; ++it) {
      const int rb = (wid * 2 + it) * 8;
      __builtin_amdgcn_global_load_lds(
          (const __attribute__((address_space(1))) void*)(A + (size_t)(m0 + rb + srow0) * 1024 + k0 + scol),
          (__attribute__((address_space(3))) void*)(&As[0][0] + (wid * 2 + it) * 512), 16, 0, 0);
    }
#pragma unroll
    for (int it = 0; it < 4; ++it) {
      const int rb = (wid * 4 + it) * 8;
      __builtin_amdgcn_global_load_lds(
          (const __attribute__((address_space(1))) void*)(B + (size_t)(n0 + rb + srow0) * 1024 + k0 + scol),
          (__attribute__((address_space(3))) void*)(&Bs[0][0] + (wid * 4 + it) * 512), 16, 0, 0);
    }
    __syncthreads();
#pragma unroll
    for (int kk = 0; kk < 64; kk += 32) {
      bf16x8 af[2], bfm[4];
      const int cs = (kk + g * 8) ^ ((li & 7) << 3);  // swizzled read col
#pragma unroll
      for (int i = 0; i < 2; ++i)
        af[i] = *reinterpret_cast<const bf16x8*>(&As[wr + i * 16 + li][cs]);
#pragma unroll
      for (int i = 0; i < 4; ++i)
        bfm[i] = *reinterpret_cast<const bf16x8*>(&Bs[wc + i * 16 + li][cs]);
#pragma unroll
      for (int mi = 0; mi < 2; ++mi)
#pragma unroll
        for (int ni = 0; ni < 4; ++ni)
          acc[mi][ni] = MFMA16(af[mi], bfm[ni], acc[mi][ni]);
    }
    __syncthreads();
  }
#pragma unroll
  for (int mi = 0; mi < 2; ++mi) {
#pragma unroll
    for (int ni = 0; ni < 4; ++ni) {
      const int col = n0 + wc + ni * 16 + li;
      const float bcol = b0[col];
#pragma unroll
      for (int r = 0; r < 4; ++r) {
        const int row = m0 + wr + mi * 16 + 4 * g + r;
        outF[(size_t)row * 1024 + col] = acc[mi][ni][r] + bcol;
      }
    }
  }
}

// ---------------- flash attention: fixed-max, split-k x4, F4 vectorized bias ----
// Best measured config: 41.4 us, VGPR 92, no spill. All occupancy/latency/fusion
// levers experimentally falsified (R5-R20); structural local minimum.
__device__ __forceinline__ void attn_phase(
    const int qt, const int wid, const int lane, const int li, const int hi,
    const int h, const int bb,
    const ushort* __restrict__ Qb, const ushort* __restrict__ Kfb,
    const ushort* __restrict__ Vfb, const float4* relv4,
    float Obuf[3][64][33], float lbuf[3][64], ushort* __restrict__ Oa) {
  const int q = qt * 32 + li;
  bf16x8 qf[4];
#pragma unroll
  for (int c = 0; c < 4; ++c)
    qf[c] = *reinterpret_cast<const bf16x8*>(Qb + (size_t)q * 64 + c * 16 + hi * 8);
  f32x16 O[2] = {};
  float lacc[4] = {0.f, 0.f, 0.f, 0.f};
  const int nkt = (qt >> 1) + 1;
  const int nt = (wid < nkt) ? ((nkt - 1 - wid) >> 2) + 1 : 0;
  const int mask_kb = (nkt - 1) * 64;
  const float C1 = 0.18033688f;               // 0.125 * log2(e)
  for (int i = 0; i < nt; ++i) {
    const int kb = wid * 64 + i * 256;
    const ushort* Kt = Kfb + (size_t)(kb >> 6) * 4096 + lane * 8;
    const ushort* Vt = Vfb + (size_t)(kb >> 6) * 4096 + lane * 8;
    bf16x8 Kr[8], Vr[8];
#pragma unroll
    for (int j = 0; j < 8; ++j)
      Kr[j] = *reinterpret_cast<const bf16x8*>(Kt + j * 512);
#pragma unroll
    for (int j = 0; j < 8; ++j)
      Vr[j] = *reinterpret_cast<const bf16x8*>(Vt + j * 512);
    __builtin_amdgcn_sched_barrier(0);
    f32x16 S0 = {}, S1 = {};
#pragma unroll
    for (int c = 0; c < 4; ++c) S0 = MFMA32(Kr[c], qf[c], S0);
#pragma unroll
    for (int c = 0; c < 4; ++c) S1 = MFMA32(Kr[4 + c], qf[c], S1);
    const int dqb = q - kb - 4 * hi;
    if (kb != mask_kb) {
#pragma unroll
      for (int rg = 0; rg < 4; ++rg) {
        const int i0 = dqb - 8 * rg, i1 = i0 - 32;
        const float4 bq0 = relv4[i0 ^ ((i0 >> 3) & 3)];
        const float4 bq1 = relv4[i1 ^ ((i1 >> 3) & 3)];
        const float b0e[4] = {bq0.x, bq0.y, bq0.z, bq0.w};
        const float b1e[4] = {bq1.x, bq1.y, bq1.z, bq1.w};
#pragma unroll
        for (int j = 0; j < 4; ++j) {
          const int r = 4 * rg + j;
          const float p0 = __builtin_amdgcn_exp2f(fmaf(S0[r], C1, b0e[j]));
          const float p1 = __builtin_amdgcn_exp2f(fmaf(S1[r], C1, b1e[j]));
          S0[r] = p0; S1[r] = p1;
          lacc[j] += p0 + p1;
        }
      }
    } else {
#pragma unroll
      for (int rg = 0; rg < 4; ++rg) {
        const int d0b = dqb - 8 * rg, d1b = d0b - 32;
        const int i0 = d0b & 2047, i1 = d1b & 2047;
        const float4 bq0 = relv4[i0 ^ ((i0 >> 3) & 3)];
        const float4 bq1 = relv4[i1 ^ ((i1 >> 3) & 3)];
        const float b0e[4] = {bq0.x, bq0.y, bq0.z, bq0.w};
        const float b1e[4] = {bq1.x, bq1.y, bq1.z, bq1.w};
#pragma unroll
        for (int j = 0; j < 4; ++j) {
          const int r = 4 * rg + j;
          float p0 = __builtin_amdgcn_exp2f(fmaf(S0[r], C1, b0e[j]));
          float p1 = __builtin_amdgcn_exp2f(fmaf(S1[r], C1, b1e[j]));
          p0 = (d0b - j >= 0) ? p0 : 0.f;
          p1 = (d1b - j >= 0) ? p1 : 0.f;
          S0[r] = p0; S1[r] = p1;
          lacc[j] += p0 + p1;
        }
      }
    }
    unsigned U0[4][2], U1[4][2];
#pragma unroll
    for (int rg = 0; rg < 4; ++rg) {
      U0[rg][0] = cvtpk(S0[4 * rg + 0], S0[4 * rg + 1]);
      U0[rg][1] = cvtpk(S0[4 * rg + 2], S0[4 * rg + 3]);
      U1[rg][0] = cvtpk(S1[4 * rg + 0], S1[4 * rg + 1]);
      U1[rg][1] = cvtpk(S1[4 * rg + 2], S1[4 * rg + 3]);
    }
#pragma unroll
    for (int c = 0; c < 4; ++c) {
      const int c0 = c & 1;
      unsigned x0 = (c < 2) ? U0[2 * c0][0] : U1[2 * c0][0];
      unsigned y0 = (c < 2) ? U0[2 * c0 + 1][0] : U1[2 * c0 + 1][0];
      unsigned x1 = (c < 2) ? U0[2 * c0][1] : U1[2 * c0][1];
      unsigned y1 = (c < 2) ? U0[2 * c0 + 1][1] : U1[2 * c0 + 1][1];
      plswap(x0, y0);
      plswap(x1, y1);
      union { unsigned u[4]; bf16x8 v; } P;
      P.u[0] = x0; P.u[1] = x1; P.u[2] = y0; P.u[3] = y1;
#pragma unroll
      for (int db = 0; db < 2; ++db)
        O[db] = MFMA32(Vr[db * 4 + c], P.v, O[db]);
    }
  }
  // -------- merge (pure sums: no max tracking) --------
  __syncthreads();   // also guards Obuf reuse across phases
  if (wid) {
    float* ob = &Obuf[wid - 1][lane][0];
#pragma unroll
    for (int db = 0; db < 2; ++db)
#pragma unroll
      for (int r = 0; r < 16; ++r)
        ob[db * 16 + r] = O[db][r];
    lbuf[wid - 1][lane] = lacc[0] + lacc[1] + lacc[2] + lacc[3];
  }
  __syncthreads();
  if (wid == 0) {
    float lh = lacc[0] + lacc[1] + lacc[2] + lacc[3];
#pragma unroll
    for (int w = 0; w < 3; ++w) {
      lh += lbuf[w][lane];
      const float* ob = &Obuf[w][lane][0];
#pragma unroll
      for (int db = 0; db < 2; ++db)
#pragma unroll
      for (int r = 0; r < 16; ++r)
          O[db][r] += ob[db * 16 + r];
    }
    unsigned xa = __float_as_uint(lh), xb2 = xa;
    plswap(xa, xb2);                      // xa = [lo|lo], xb2 = [hi|hi]
    const float linv = 1.f / (__uint_as_float(xa) + __uint_as_float(xb2));
    ushort* orow = Oa + ((size_t)(bb * 2048 + q)) * 1024 + h * 64;
#pragma unroll
    for (int db = 0; db < 2; ++db)
#pragma unroll
      for (int rg = 0; rg < 4; ++rg) {
        ushort4 o;
        o.x = f2b(O[db][4 * rg + 0] * linv);
        o.y = f2b(O[db][4 * rg + 1] * linv);
        o.z = f2b(O[db][4 * rg + 2] * linv);
        o.w = f2b(O[db][4 * rg + 3] * linv);
        *reinterpret_cast<ushort4*>(orow + db * 32 + 8 * rg + 4 * hi) = o;
      }
  }
}

// grid: 1024 blocks = (bh, qp); block does q-tiles qp and 63-qp -> constant work.
__global__ __launch_bounds__(256, 2)
void attn_k(const ushort* __restrict__ Qg, const ushort* __restrict__ Kf,
            const ushort* __restrict__ Vf, const float4* __restrict__ relF4,
            ushort* __restrict__ Oa) {
  __shared__ __align__(16) float4 relv4[2048];
  __shared__ float Obuf[3][64][33];
  __shared__ float lbuf[3][64];
  const int f = blockIdx.x;
  const int bh = (f & 7) * 4 + (f >> 8);      // same bh -> same XCD
  const int qp = (f >> 3) & 31;
  const int h = bh & 15, bb = bh >> 4;
  {
    const float4* src = relF4 + (size_t)h * 2048;
    for (int i = threadIdx.x; i < 2048; i += 256)
      relv4[i ^ ((i >> 3) & 3)] = src[i];
  }
  __syncthreads();
  const int wid = threadIdx.x >> 6, lane = threadIdx.x & 63;
  const int li = lane & 31, hi = lane >> 5;
  const ushort* Qb  = Qg + (size_t)bh * (2048 * 64);
  const ushort* Kfb = Kf + (size_t)bh * (32 * 4096);
  const ushort* Vfb = Vf + (size_t)bh * (32 * 4096);
  attn_phase(qp,      wid, lane, li, hi, h, bb, Qb, Kfb, Vfb, relv4, Obuf, lbuf, Oa);
  attn_phase(63 - qp, wid, lane, li, hi, h, bb, Qb, Kfb, Vfb, relv4, Obuf, lbuf, Oa);
}

extern "C" void kernel_launch(void* const* d_in, const int* in_sizes, int n_in,
                              void* d_out, int out_size, void* d_ws, size_t ws_size,
                              hipStream_t stream) {
  const float* x    = (const float*)d_in[0];
  const float* WQ   = (const float*)d_in[1];
  const float* bQ   = (const float*)d_in[2];
  const float* WK   = (const float*)d_in[3];
  const float* bK   = (const float*)d_in[4];
  const float* WV   = (const float*)d_in[5];
  const float* bV   = (const float*)d_in[6];
  const float* WO   = (const float*)d_in[7];
  const float* bO   = (const float*)d_in[8];
  const float* relT = (const float*)d_in[9];
  float* out = (float*)d_out;

  if (ws_size < (size_t)48 * 1024 * 1024) return;

  char* ws = (char*)d_ws;
  const size_t MB = 1024 * 1024;
  // timeline: xb (0-8M) dead after gemm1 -> Oa reuses it; relF4 at 40M.
  ushort* xb    = (ushort*)(ws);             // [4096][1024] bf16; dead after gemm1
  ushort* Oa    = (ushort*)(ws);             // attn out bf16, overlays dead xb
  ushort* Wcat  = (ushort*)(ws + 8 * MB);    // [3072][1024] bf16
  ushort* WOb   = (ushort*)(ws + 14 * MB);   // [1024][1024] bf16
  ushort* Qg    = (ushort*)(ws + 16 * MB);   // [2,16,2048,64] bf16
  ushort* Kf    = (ushort*)(ws + 24 * MB);   // K fragment-order (8MB)
  ushort* Vf    = (ushort*)(ws + 32 * MB);   // V fragment-order (8MB)
  float4* relF4 = (float4*)(ws + 40 * MB);   // [16][2048] f32x4 (512KB)

  prep_cast<<<8320, 256, 0, stream>>>(x, WQ, WK, WV, WO, relT, xb, Wcat, WOb, relF4);
  gemm_bt<<<dim3(24, 32), 256, 0, stream>>>(xb, Wcat, bQ, bK, bV, Qg, Kf, Vf);
  attn_k<<<1024, 256, 0, stream>>>(Qg, Kf, Vf, relF4, Oa);
  gemm_o<<<dim3(8, 64), 256, 0, stream>>>(Oa, WOb, bO, out);
}